// Round 10
// baseline (981.899 us; speedup 1.0000x reference)
//
#include <hip/hip_runtime.h>
#include <stdint.h>

typedef unsigned short u16;
typedef __bf16 bf16x8 __attribute__((ext_vector_type(8)));
typedef float f32x4 __attribute__((ext_vector_type(4)));

#define B_    2
#define C_    256
#define N_    40962
#define BN_   (B_ * N_)          // 81924
#define H_    8
#define HD_   32
#define NTOP  2562
#define TOPW  16
#define NDOWN 2562
#define DOWNW 19
#define M_    (NTOP*TOPW + NDOWN*DOWNW)   // 89670
#define SCALE_ 0.17677669529663687f       // 32^-0.5
#define BN_EPS 1e-5f

// res2 is INTERLEAVED into qkvres's dead k/v columns (cols 256..767 of each
// 1024-u16 row): float index = row*512 + 128 + col. Race-free vs xf/res reads.
#define RES2_IDX(row, col) ((size_t)(row) * 512 + 128 + (col))

// ---------- bf16 helpers (raw u16 storage) ----------
__device__ __forceinline__ float b2f(u16 u) {
    union { uint32_t i; float f; } v; v.i = ((uint32_t)u) << 16; return v.f;
}
__device__ __forceinline__ u16 f2b(float f) {
    union { float f; uint32_t i; } v; v.f = f;
    uint32_t r = v.i + 0x7fffu + ((v.i >> 16) & 1u);   // RNE
    return (u16)(r >> 16);
}
// adaptive load: element i of a float tensor that is either f32 (isf32=1) or bf16
__device__ __forceinline__ float ld(const void* p, size_t i, int isf32) {
    return isf32 ? ((const float*)p)[i] : b2f(((const u16*)p)[i]);
}

// bijective XCD swizzle for grid=1281 (m204 formula; 1281 = 8*160 + 1)
__device__ __forceinline__ int xcd_swz_1281(int bx) {
    const int q = 160, r = 1;
    int xcd = bx & 7, o = bx >> 3;
    return (xcd < r ? xcd * (q + 1) : r * (q + 1) + (xcd - r) * q) + o;
}

// ---------- dtype probe: even u16 indices are garbage iff data is f32 ----------
__global__ void probe_k(const void* __restrict__ x, int* __restrict__ flag) {
    int lane = threadIdx.x;
    u16 v = ((const u16*)x)[2 * lane];
    int e = (v >> 7) & 0xff;
    bool ok = (e >= 118 && e <= 134);   // |val| in ~[2^-9, 2^8] -> plausible N(0,1) bf16
    unsigned long long m = __ballot(ok);
    if (lane == 0) *flag = (__popcll(m) < 32) ? 1 : 0;   // 1 = f32 inputs
}

// ---------- small prep kernels (dtype-adaptive) ----------
// Writes TRANSPOSED weights: WcatT[j][k] (1024x256), WprojT[j][k] (256x256)
__global__ void wcat_k(const void* __restrict__ Wqkv, const void* __restrict__ Wres,
                       const void* __restrict__ Wproj,
                       u16* __restrict__ WcatT, u16* __restrict__ WprojT,
                       const int* __restrict__ flag) {
    const int f = *flag;
    int k = blockIdx.x, t = threadIdx.x;
    for (int j = t; j < 768; j += 256) WcatT[(size_t)j * 256 + k] = f2b(ld(Wqkv, (size_t)k * 768 + j, f));
    WcatT[(size_t)(768 + t) * 256 + k] = f2b(ld(Wres, (size_t)k * 256 + t, f));
    WprojT[(size_t)t * 256 + k] = f2b(ld(Wproj, (size_t)k * 256 + t, f));
}

__global__ void biasprep_k(const void* bqkv, const void* bres, const void* bproj,
                           float* bias_cat, float* bias_proj, const int* __restrict__ flag) {
    const int f = *flag;
    int g = blockIdx.x * 256 + threadIdx.x;
    if (g < 768) bias_cat[g] = ld(bqkv, g, f);
    else if (g < 1024) bias_cat[g] = ld(bres, g - 768, f);
    else if (g < 1280) bias_proj[g - 1024] = ld(bproj, g - 1024, f);
}

// WfT[t][i] = (Wm1 @ Wm2)[i][t]   (transposed product), bf16 out
__global__ __launch_bounds__(256) void wf_k(const void* __restrict__ Wm1, const void* __restrict__ Wm2,
                                            u16* __restrict__ WfT, const int* __restrict__ flag) {
    const int f = *flag;
    __shared__ float row[512];
    int i = blockIdx.x, t = threadIdx.x;
    row[t] = ld(Wm1, (size_t)i * 512 + t, f);
    row[t + 256] = ld(Wm1, (size_t)i * 512 + 256 + t, f);
    __syncthreads();
    float acc = 0.f;
    for (int k = 0; k < 512; ++k) acc += row[k] * ld(Wm2, (size_t)k * 256 + t, f);
    WfT[(size_t)t * 256 + i] = f2b(acc);
}

// bf = bm1 @ Wm2 + bm2   (f32)
__global__ void bf_k(const void* bm1, const void* __restrict__ Wm2, const void* bm2,
                     float* bf, const int* __restrict__ flag) {
    const int f = *flag;
    int t = threadIdx.x;
    float acc = ld(bm2, t, f);
    for (int k = 0; k < 512; ++k) acc += ld(bm1, k, f) * ld(Wm2, (size_t)k * 256 + t, f);
    bf[t] = acc;
}

// ---------- QKV(+res) GEMM: A->LDS once (1 barrier), paired B register bursts ----------
// Out(BN x 1024) = X^T(BN x 256) @ Wcat(256 x 1024) + bias_cat
// Per pair: issue 16 B loads (2 tiles), compute tile A under tile B's load latency.
__global__ __launch_bounds__(256) void gemm_qkv_k(
    const void* __restrict__ x, const u16* __restrict__ WcatT,
    const float* __restrict__ bias, u16* __restrict__ Out, const int* __restrict__ flag)
{
    const int isf32 = *flag;
    __shared__ __align__(16) u16 As[64][264];
    const int tid = threadIdx.x;
    const int bx = xcd_swz_1281(blockIdx.x);
    const int R0 = bx * 64;
    const int wave = tid >> 6, lane = tid & 63;
    const int quad = lane >> 4, mrow = lane & 15;

    // ---- stage A once into LDS ----
    const bool fastA = (R0 + 64 <= N_) || (R0 >= N_ && R0 + 64 <= BN_);
    if (fastA) {
        const int b = (R0 >= N_) ? 1 : 0;
        const int nn = R0 - b * N_;
        const int k = tid;
        if (isf32) {
            const float* xp = (const float*)x + (size_t)(b * 256 + k) * N_ + nn;
#pragma unroll
            for (int j = 0; j < 32; ++j) {
                float2 v = *reinterpret_cast<const float2*>(xp + 2 * j);
                As[2 * j][k] = f2b(v.x);
                As[2 * j + 1][k] = f2b(v.y);
            }
        } else {
            const u16* xp = (const u16*)x + (size_t)(b * 256 + k) * N_ + nn;
#pragma unroll
            for (int j = 0; j < 32; ++j) {
                uint32_t v = *reinterpret_cast<const uint32_t*>(xp + 2 * j);
                As[2 * j][k] = (u16)v;
                As[2 * j + 1][k] = (u16)(v >> 16);
            }
        }
    } else {
        const int n = tid & 63;
        const int kg = tid >> 6;
        const int g = R0 + n;
        const bool valid = (g < BN_);
        const int b = (g >= N_) ? 1 : 0;
        const int nn = g - b * N_;
#pragma unroll
        for (int j = 0; j < 8; ++j) {
            const int k0 = kg * 8 + j * 32;
            u16 tmp[8];
            if (valid) {
#pragma unroll
                for (int i = 0; i < 8; ++i) tmp[i] = f2b(ld(x, (size_t)(b * 256 + k0 + i) * N_ + nn, isf32));
            } else {
#pragma unroll
                for (int i = 0; i < 8; ++i) tmp[i] = 0;
            }
            *reinterpret_cast<uint4*>(&As[n][k0]) = *reinterpret_cast<const uint4*>(tmp);
        }
    }
    __syncthreads();   // the ONLY barrier

    for (int cp = 0; cp < 8; ++cp) {
        const int colA = (cp * 2) * 64 + wave * 16 + mrow;
        const int colB = colA + 64;
        const u16* bpA = WcatT + (size_t)colA * 256 + quad * 8;
        const u16* bpB = WcatT + (size_t)colB * 256 + quad * 8;
        uint4 bregA[8], bregB[8];
#pragma unroll
        for (int kc = 0; kc < 8; ++kc) bregA[kc] = *reinterpret_cast<const uint4*>(bpA + kc * 32);
#pragma unroll
        for (int kc = 0; kc < 8; ++kc) bregB[kc] = *reinterpret_cast<const uint4*>(bpB + kc * 32);
        // ---- tile A (B's loads still in flight) ----
        f32x4 acc[4] = {f32x4{0,0,0,0}, f32x4{0,0,0,0}, f32x4{0,0,0,0}, f32x4{0,0,0,0}};
#pragma unroll
        for (int kc = 0; kc < 8; ++kc) {
            bf16x8 bfrag = *reinterpret_cast<const bf16x8*>(&bregA[kc]);
#pragma unroll
            for (int t2 = 0; t2 < 4; ++t2) {
                bf16x8 afrag = *reinterpret_cast<const bf16x8*>(&As[t2 * 16 + mrow][kc * 32 + quad * 8]);
                acc[t2] = __builtin_amdgcn_mfma_f32_16x16x32_bf16(afrag, bfrag, acc[t2], 0, 0, 0);
            }
        }
        {
            const float bcol = bias[colA];
#pragma unroll
            for (int t2 = 0; t2 < 4; ++t2)
#pragma unroll
                for (int r = 0; r < 4; ++r) {
                    int row = R0 + t2 * 16 + quad * 4 + r;
                    if (row < BN_) Out[(size_t)row * 1024 + colA] = f2b(acc[t2][r] + bcol);
                }
        }
        // ---- tile B ----
#pragma unroll
        for (int t2 = 0; t2 < 4; ++t2) acc[t2] = f32x4{0,0,0,0};
#pragma unroll
        for (int kc = 0; kc < 8; ++kc) {
            bf16x8 bfrag = *reinterpret_cast<const bf16x8*>(&bregB[kc]);
#pragma unroll
            for (int t2 = 0; t2 < 4; ++t2) {
                bf16x8 afrag = *reinterpret_cast<const bf16x8*>(&As[t2 * 16 + mrow][kc * 32 + quad * 8]);
                acc[t2] = __builtin_amdgcn_mfma_f32_16x16x32_bf16(afrag, bfrag, acc[t2], 0, 0, 0);
            }
        }
        {
            const float bcol = bias[colB];
#pragma unroll
            for (int t2 = 0; t2 < 4; ++t2)
#pragma unroll
                for (int r = 0; r < 4; ++r) {
                    int row = R0 + t2 * 16 + quad * 4 + r;
                    if (row < BN_) Out[(size_t)row * 1024 + colB] = f2b(acc[t2][r] + bcol);
                }
        }
    }
}

// ---------- fused MLP: out = xf@Wproj+bproj+res -> outb; res2 = out@Wf+bf ----------
// res2 written into qkvres's dead k/v columns via RES2_IDX (race-free).
__global__ __launch_bounds__(256) void gemm_mlp_k(
    const u16* __restrict__ xf, const u16* __restrict__ WprojT, const float* __restrict__ bproj,
    const u16* __restrict__ resp, const u16* __restrict__ WfT, const float* __restrict__ bfv,
    u16* __restrict__ outb, float* __restrict__ res2)
{
    __shared__ __align__(16) u16 As[64][264];
    const int tid = threadIdx.x;
    const int bx = xcd_swz_1281(blockIdx.x);
    const int R0 = bx * 64;
    const int wave = tid >> 6, lane = tid & 63;
    const int quad = lane >> 4, mrow = lane & 15;

    // ---- stage xf tile (ldA = 1024) ----
#pragma unroll
    for (int it = 0; it < 8; ++it) {
        int e = it * 256 + tid;
        int row = e >> 5, ks = (e & 31) * 8;
        uint4 v = make_uint4(0u, 0u, 0u, 0u);
        if (R0 + row < BN_)
            v = *reinterpret_cast<const uint4*>(xf + (size_t)(R0 + row) * 1024 + ks);
        *reinterpret_cast<uint4*>(&As[row][ks]) = v;
    }
    __syncthreads();

    // ---- GEMM1: out = xf @ Wproj + bproj + res ----
    for (int cp = 0; cp < 2; ++cp) {
        const int colA = cp * 128 + wave * 16 + mrow;
        const int colB = colA + 64;
        const u16* bpA = WprojT + (size_t)colA * 256 + quad * 8;
        const u16* bpB = WprojT + (size_t)colB * 256 + quad * 8;
        uint4 bregA[8], bregB[8];
#pragma unroll
        for (int kc = 0; kc < 8; ++kc) bregA[kc] = *reinterpret_cast<const uint4*>(bpA + kc * 32);
#pragma unroll
        for (int kc = 0; kc < 8; ++kc) bregB[kc] = *reinterpret_cast<const uint4*>(bpB + kc * 32);
        f32x4 acc[4] = {f32x4{0,0,0,0}, f32x4{0,0,0,0}, f32x4{0,0,0,0}, f32x4{0,0,0,0}};
#pragma unroll
        for (int kc = 0; kc < 8; ++kc) {
            bf16x8 bfrag = *reinterpret_cast<const bf16x8*>(&bregA[kc]);
#pragma unroll
            for (int t2 = 0; t2 < 4; ++t2) {
                bf16x8 afrag = *reinterpret_cast<const bf16x8*>(&As[t2 * 16 + mrow][kc * 32 + quad * 8]);
                acc[t2] = __builtin_amdgcn_mfma_f32_16x16x32_bf16(afrag, bfrag, acc[t2], 0, 0, 0);
            }
        }
        {
            const float bcol = bproj[colA];
#pragma unroll
            for (int t2 = 0; t2 < 4; ++t2)
#pragma unroll
                for (int r = 0; r < 4; ++r) {
                    int row = R0 + t2 * 16 + quad * 4 + r;
                    if (row < BN_) {
                        float v = acc[t2][r] + bcol + b2f(resp[(size_t)row * 1024 + colA]);
                        outb[(size_t)row * 256 + colA] = f2b(v);
                    }
                }
        }
#pragma unroll
        for (int t2 = 0; t2 < 4; ++t2) acc[t2] = f32x4{0,0,0,0};
#pragma unroll
        for (int kc = 0; kc < 8; ++kc) {
            bf16x8 bfrag = *reinterpret_cast<const bf16x8*>(&bregB[kc]);
#pragma unroll
            for (int t2 = 0; t2 < 4; ++t2) {
                bf16x8 afrag = *reinterpret_cast<const bf16x8*>(&As[t2 * 16 + mrow][kc * 32 + quad * 8]);
                acc[t2] = __builtin_amdgcn_mfma_f32_16x16x32_bf16(afrag, bfrag, acc[t2], 0, 0, 0);
            }
        }
        {
            const float bcol = bproj[colB];
#pragma unroll
            for (int t2 = 0; t2 < 4; ++t2)
#pragma unroll
                for (int r = 0; r < 4; ++r) {
                    int row = R0 + t2 * 16 + quad * 4 + r;
                    if (row < BN_) {
                        float v = acc[t2][r] + bcol + b2f(resp[(size_t)row * 1024 + colB]);
                        outb[(size_t)row * 256 + colB] = f2b(v);
                    }
                }
        }
    }
    __syncthreads();   // drains vmcnt -> our outb stores are visible to our own reads

    // ---- restage out tile from global (L2-hot: we just wrote it on this CU) ----
#pragma unroll
    for (int it = 0; it < 8; ++it) {
        int e = it * 256 + tid;
        int row = e >> 5, ks = (e & 31) * 8;
        uint4 v = make_uint4(0u, 0u, 0u, 0u);
        if (R0 + row < BN_)
            v = *reinterpret_cast<const uint4*>(outb + (size_t)(R0 + row) * 256 + ks);
        *reinterpret_cast<uint4*>(&As[row][ks]) = v;
    }
    __syncthreads();

    // ---- GEMM2: res2 = out @ Wf + bf (f32, interleaved layout) ----
    for (int cp = 0; cp < 2; ++cp) {
        const int colA = cp * 128 + wave * 16 + mrow;
        const int colB = colA + 64;
        const u16* bpA = WfT + (size_t)colA * 256 + quad * 8;
        const u16* bpB = WfT + (size_t)colB * 256 + quad * 8;
        uint4 bregA[8], bregB[8];
#pragma unroll
        for (int kc = 0; kc < 8; ++kc) bregA[kc] = *reinterpret_cast<const uint4*>(bpA + kc * 32);
#pragma unroll
        for (int kc = 0; kc < 8; ++kc) bregB[kc] = *reinterpret_cast<const uint4*>(bpB + kc * 32);
        f32x4 acc[4] = {f32x4{0,0,0,0}, f32x4{0,0,0,0}, f32x4{0,0,0,0}, f32x4{0,0,0,0}};
#pragma unroll
        for (int kc = 0; kc < 8; ++kc) {
            bf16x8 bfrag = *reinterpret_cast<const bf16x8*>(&bregA[kc]);
#pragma unroll
            for (int t2 = 0; t2 < 4; ++t2) {
                bf16x8 afrag = *reinterpret_cast<const bf16x8*>(&As[t2 * 16 + mrow][kc * 32 + quad * 8]);
                acc[t2] = __builtin_amdgcn_mfma_f32_16x16x32_bf16(afrag, bfrag, acc[t2], 0, 0, 0);
            }
        }
        {
            const float bcol = bfv[colA];
#pragma unroll
            for (int t2 = 0; t2 < 4; ++t2)
#pragma unroll
                for (int r = 0; r < 4; ++r) {
                    int row = R0 + t2 * 16 + quad * 4 + r;
                    if (row < BN_) res2[RES2_IDX(row, colA)] = acc[t2][r] + bcol;
                }
        }
#pragma unroll
        for (int t2 = 0; t2 < 4; ++t2) acc[t2] = f32x4{0,0,0,0};
#pragma unroll
        for (int kc = 0; kc < 8; ++kc) {
            bf16x8 bfrag = *reinterpret_cast<const bf16x8*>(&bregB[kc]);
#pragma unroll
            for (int t2 = 0; t2 < 4; ++t2) {
                bf16x8 afrag = *reinterpret_cast<const bf16x8*>(&As[t2 * 16 + mrow][kc * 32 + quad * 8]);
                acc[t2] = __builtin_amdgcn_mfma_f32_16x16x32_bf16(afrag, bfrag, acc[t2], 0, 0, 0);
            }
        }
        {
            const float bcol = bfv[colB];
#pragma unroll
            for (int t2 = 0; t2 < 4; ++t2)
#pragma unroll
                for (int r = 0; r < 4; ++r) {
                    int row = R0 + t2 * 16 + quad * 4 + r;
                    if (row < BN_) res2[RES2_IDX(row, colB)] = acc[t2][r] + bcol;
                }
        }
    }
}

// ---------- window attention (one block = one window x one batch, all 8 heads) ----------
template<int W>
__global__ __launch_bounds__(256) void attn_k(const u16* __restrict__ qkv, const int* __restrict__ widx,
                                              u16* __restrict__ xw, int mbase)
{
    const int w = blockIdx.x, b = blockIdx.y;
    const int tid = threadIdx.x;
    __shared__ int wi[W];
    __shared__ __align__(16) float Ks[W][H_][36];
    __shared__ __align__(16) float Vs[W][H_][36];
    if (tid < W) wi[tid] = widx[w * W + tid];
    __syncthreads();
    for (int e = tid; e < W * 32; e += 256) {
        int j = e >> 5, seg = e & 31;
        size_t base = ((size_t)(b * N_ + wi[j])) * 1024 + 256 + seg * 8;
        uint4 kv = *reinterpret_cast<const uint4*>(qkv + base);         // K
        uint4 vv = *reinterpret_cast<const uint4*>(qkv + base + 256);   // V
        int h = seg >> 2, c0 = (seg & 3) * 8;
        const u16* kp = (const u16*)&kv; const u16* vp = (const u16*)&vv;
#pragma unroll
        for (int t = 0; t < 8; ++t) {
            Ks[j][h][c0 + t] = b2f(kp[t]);
            Vs[j][h][c0 + t] = b2f(vp[t]);
        }
    }
    __syncthreads();

    if (tid < W * H_) {
        const int j = tid >> 3, h = tid & 7;
        float qr[32];
        {
            size_t qb = ((size_t)(b * N_ + wi[j])) * 1024 + h * 32;
#pragma unroll
            for (int s4 = 0; s4 < 4; ++s4) {
                uint4 qv = *reinterpret_cast<const uint4*>(qkv + qb + s4 * 8);
                const u16* qp = (const u16*)&qv;
#pragma unroll
                for (int t = 0; t < 8; ++t) qr[s4 * 8 + t] = b2f(qp[t]) * SCALE_;
            }
        }
        float p[W];
        float mx = -1e30f;
#pragma unroll
        for (int jj = 0; jj < W; ++jj) {
            const float* kr = &Ks[jj][h][0];
            float s = 0.f;
#pragma unroll
            for (int c = 0; c < 32; ++c) s += qr[c] * kr[c];
            p[jj] = s;
            mx = fmaxf(mx, s);
        }
        float sum = 0.f;
#pragma unroll
        for (int jj = 0; jj < W; ++jj) { p[jj] = __expf(p[jj] - mx); sum += p[jj]; }
        const float inv = 1.0f / sum;
        float o[32];
#pragma unroll
        for (int c = 0; c < 32; ++c) o[c] = 0.f;
#pragma unroll
        for (int jj = 0; jj < W; ++jj) {
            const float pj = p[jj];
            const float* vr = &Vs[jj][h][0];
#pragma unroll
            for (int c = 0; c < 32; ++c) o[c] += pj * vr[c];
        }
        const int m = mbase + w * W + j;
        size_t off = ((size_t)b * (M_ + 1) + m) * 256 + h * 32;
#pragma unroll
        for (int s4 = 0; s4 < 4; ++s4) {
            uint32_t w0 = (uint32_t)f2b(o[s4 * 8 + 0] * inv) | ((uint32_t)f2b(o[s4 * 8 + 1] * inv) << 16);
            uint32_t w1 = (uint32_t)f2b(o[s4 * 8 + 2] * inv) | ((uint32_t)f2b(o[s4 * 8 + 3] * inv) << 16);
            uint32_t w2 = (uint32_t)f2b(o[s4 * 8 + 4] * inv) | ((uint32_t)f2b(o[s4 * 8 + 5] * inv) << 16);
            uint32_t w3 = (uint32_t)f2b(o[s4 * 8 + 6] * inv) | ((uint32_t)f2b(o[s4 * 8 + 7] * inv) << 16);
            *reinterpret_cast<uint4*>(xw + off + s4 * 8) = make_uint4(w0, w1, w2, w3);
        }
    }
}

// ---------- gather + average -> xf written into qkvres cols 0..255 (ld 1024) ----------
__global__ __launch_bounds__(256) void gather_k(const u16* __restrict__ xw, const int* __restrict__ rev,
                                                const void* __restrict__ cnt_inv, u16* __restrict__ xfp,
                                                int K, const int* __restrict__ flag)
{
    const int f = *flag;
    int gid = blockIdx.x * 4 + (threadIdx.x >> 6);
    if (gid >= BN_) return;
    int b = (gid >= N_) ? 1 : 0;
    int n = gid - b * N_;
    int c4 = (threadIdx.x & 63) * 4;
    float a0 = 0, a1 = 0, a2 = 0, a3 = 0;
    const int* rp = rev + (size_t)n * K;
    for (int k = 0; k < K; ++k) {
        int idx = rp[k];
        if (idx < M_) {
            ushort4 v = *reinterpret_cast<const ushort4*>(xw + ((size_t)b * (M_ + 1) + idx) * 256 + c4);
            a0 += b2f(v.x); a1 += b2f(v.y); a2 += b2f(v.z); a3 += b2f(v.w);
        }
    }
    float ci = ld(cnt_inv, n, f);
    ushort4 o;
    o.x = f2b(a0 * ci); o.y = f2b(a1 * ci); o.z = f2b(a2 * ci); o.w = f2b(a3 * ci);
    *reinterpret_cast<ushort4*>(xfp + (size_t)gid * 1024 + c4) = o;
}

// ---------- BN stats over res2 (interleaved layout): per-column sum & sumsq ----------
#define STATS_BLOCKS 512
__global__ __launch_bounds__(256) void stats_k(const float* __restrict__ res2, float* __restrict__ sums) {
    const int tid = threadIdx.x;
    const int c4 = (tid & 63) * 4;    // column group
    const int rsub = tid >> 6;        // 0..3 (which row of the 4-row slab)
    float s[4] = {0.f, 0.f, 0.f, 0.f};
    float q[4] = {0.f, 0.f, 0.f, 0.f};
    for (int r = blockIdx.x * 4 + rsub; r < BN_; r += STATS_BLOCKS * 4) {
        float4 v = *reinterpret_cast<const float4*>(res2 + RES2_IDX(r, c4));
        s[0] += v.x; q[0] += v.x * v.x;
        s[1] += v.y; q[1] += v.y * v.y;
        s[2] += v.z; q[2] += v.z * v.z;
        s[3] += v.w; q[3] += v.w * v.w;
    }
    __shared__ float rs[256][4];
    __shared__ float rq[256][4];
#pragma unroll
    for (int j = 0; j < 4; ++j) { rs[tid][j] = s[j]; rq[tid][j] = q[j]; }
    __syncthreads();
    if (tid < 64) {
#pragma unroll
        for (int j = 0; j < 4; ++j) {
            float a = rs[tid][j] + rs[tid + 64][j] + rs[tid + 128][j] + rs[tid + 192][j];
            float b = rq[tid][j] + rq[tid + 64][j] + rq[tid + 128][j] + rq[tid + 192][j];
            atomicAdd(&sums[c4 + j], a);
            atomicAdd(&sums[256 + c4 + j], b);
        }
    }
}

__global__ void bnfin_k(const float* sums, const void* gamma, const void* beta, float* ss,
                        const int* __restrict__ flag) {
    const int f = *flag;
    int c = threadIdx.x;
    float mean = sums[c] * (1.0f / BN_);
    float var = sums[256 + c] * (1.0f / BN_) - mean * mean;
    float inv = rsqrtf(fmaxf(var, 0.f) + BN_EPS);
    float sc = ld(gamma, c, f) * inv;
    ss[c] = sc;
    ss[256 + c] = ld(beta, c, f) - mean * sc;
}

// ---------- final: y[b,oc,n] = out[b,n,oc] + res2[b,n,oc]*scale[oc] + shift[oc] ----------
__global__ __launch_bounds__(256) void final_k(const u16* __restrict__ outb, const float* __restrict__ res2,
                                               const float* __restrict__ ss, void* __restrict__ y,
                                               const int* __restrict__ flag)
{
    const int isf32 = *flag;
    __shared__ __align__(16) float tile[64][65];
    const int n0 = blockIdx.x * 64, o0 = blockIdx.y * 64, b = blockIdx.z;
    const int tid = threadIdx.x;
    {
        const int ln = tid >> 2, os = (tid & 3) * 16;
        int n = n0 + ln;
        if (n < N_) {
            size_t row = (size_t)(b * N_ + n);
            size_t base = row * 256 + o0 + os;
            uint4 ov0 = *reinterpret_cast<const uint4*>(outb + base);
            uint4 ov1 = *reinterpret_cast<const uint4*>(outb + base + 8);
            const u16* op = (const u16*)&ov0;
            const u16* op1 = (const u16*)&ov1;
            float4 rv[4];
#pragma unroll
            for (int q = 0; q < 4; ++q)
                rv[q] = *reinterpret_cast<const float4*>(res2 + RES2_IDX(row, o0 + os + q * 4));
            const float* rp = (const float*)&rv[0];
#pragma unroll
            for (int j = 0; j < 16; ++j) {
                int oc = o0 + os + j;
                float ob = (j < 8) ? b2f(op[j]) : b2f(op1[j - 8]);
                tile[ln][os + j] = ob + rp[j] * ss[oc] + ss[256 + oc];
            }
        }
    }
    __syncthreads();
    {
        const int wave = tid >> 6, lane = tid & 63;
        int n = n0 + lane;
        if (n < N_) {
            if (isf32) {
                float* yp = (float*)y;
#pragma unroll
                for (int r0 = 0; r0 < 64; r0 += 4) {
                    int r = r0 + wave;
                    int oc = o0 + r;
                    yp[((size_t)(b * 256 + oc)) * N_ + n] = tile[lane][r];
                }
            } else {
                u16* yp = (u16*)y;
#pragma unroll
                for (int r0 = 0; r0 < 64; r0 += 4) {
                    int r = r0 + wave;
                    int oc = o0 + r;
                    yp[((size_t)(b * 256 + oc)) * N_ + n] = f2b(tile[lane][r]);
                }
            }
        }
    }
}

// ---------- workspace layout (bytes) ----------
static const size_t OFF_QKV   = 0;
static const size_t OFF_XW    = 167780352;
static const size_t OFF_SMALL = 259603456;

extern "C" void kernel_launch(void* const* d_in, const int* in_sizes, int n_in,
                              void* d_out, int out_size, void* d_ws, size_t ws_size,
                              hipStream_t stream) {
    const void* x     = d_in[0];
    const void* Wqkv  = d_in[1];
    const void* bqkv  = d_in[2];
    const void* Wproj = d_in[3];
    const void* bproj = d_in[4];
    const void* Wres  = d_in[5];
    const void* bres  = d_in[6];
    const void* Wm1   = d_in[7];
    const void* bm1   = d_in[8];
    const void* Wm2   = d_in[9];
    const void* bm2   = d_in[10];
    const void* gamma = d_in[11];
    const void* beta  = d_in[12];
    const void* cnt_inv = d_in[13];
    const int* top_idx = (const int*)d_in[14];
    const int* down_idx = (const int*)d_in[15];
    const int* rev   = (const int*)d_in[16];
    const int K = in_sizes[16] / N_;

    char* ws = (char*)d_ws;
    u16*  qkvres  = (u16*)(ws + OFF_QKV);
    float* res2   = (float*)(ws + OFF_QKV);   // interleaved via RES2_IDX
    u16*  xw      = (u16*)(ws + OFF_XW);
    u16*  outb    = (u16*)(ws + OFF_XW);
    u16*  WcatT   = (u16*)(ws + OFF_SMALL);
    u16*  WfT     = (u16*)(ws + OFF_SMALL + 524288);
    float* bias_cat  = (float*)(ws + OFF_SMALL + 655360);
    float* bias_proj = (float*)(ws + OFF_SMALL + 659456);
    float* bfv       = (float*)(ws + OFF_SMALL + 663552);
    float* stats     = (float*)(ws + OFF_SMALL + 667648);
    float* ssbuf     = (float*)(ws + OFF_SMALL + 671744);
    int*   flag      = (int*)(ws + OFF_SMALL + 675840);
    u16*  WprojT     = (u16*)(ws + OFF_SMALL + 679936);   // 131072 bytes

    // dtype probe first
    probe_k<<<1, 64, 0, stream>>>(x, flag);

    // prep (dtype-adaptive, transposed weights)
    wcat_k<<<256, 256, 0, stream>>>(Wqkv, Wres, Wproj, WcatT, WprojT, flag);
    biasprep_k<<<5, 256, 0, stream>>>(bqkv, bres, bproj, bias_cat, bias_proj, flag);
    wf_k<<<256, 256, 0, stream>>>(Wm1, Wm2, WfT, flag);
    bf_k<<<1, 256, 0, stream>>>(bm1, Wm2, bm2, bfv, flag);

    // qkv + res fused GEMM straight from x: (BN,256) @ (256,1024)
    gemm_qkv_k<<<1281, 256, 0, stream>>>(x, WcatT, bias_cat, qkvres, flag);

    // window attention: one block per (window, batch), all heads
    attn_k<TOPW><<<dim3(NTOP, B_), 256, 0, stream>>>(qkvres, top_idx, xw, 0);
    attn_k<DOWNW><<<dim3(NDOWN, B_), 256, 0, stream>>>(qkvres, down_idx, xw, NTOP * TOPW);

    // scatter-average back to points -> xf = qkvres cols 0..255 (q is dead)
    gather_k<<<(BN_ + 3) / 4, 256, 0, stream>>>(xw, rev, cnt_inv, qkvres, K, flag);

    // fused: out = xf@Wproj+bproj+res -> outb; res2 = out@(Wm1@Wm2)+bf (interleaved)
    gemm_mlp_k<<<1281, 256, 0, stream>>>(
        qkvres, WprojT, bias_proj, qkvres + 768, WfT, bfv, outb, res2);

    // batchnorm stats + finalize
    (void)hipMemsetAsync(stats, 0, 512 * sizeof(float), stream);
    stats_k<<<STATS_BLOCKS, 256, 0, stream>>>(res2, stats);
    bnfin_k<<<1, 256, 0, stream>>>(stats, gamma, beta, ssbuf, flag);

    // fused transpose + BN + residual add -> y (B, 256, N), dtype per flag
    final_k<<<dim3(641, 4, 2), 256, 0, stream>>>(outb, res2, ssbuf, d_out, flag);
}

// Round 12
// 951.764 us; speedup vs baseline: 1.0317x; 1.0317x over previous
//
#include <hip/hip_runtime.h>
#include <stdint.h>

typedef unsigned short u16;
typedef __bf16 bf16x8 __attribute__((ext_vector_type(8)));
typedef float f32x4 __attribute__((ext_vector_type(4)));

#define B_    2
#define C_    256
#define N_    40962
#define BN_   (B_ * N_)          // 81924
#define H_    8
#define HD_   32
#define NTOP  2562
#define TOPW  16
#define NDOWN 2562
#define DOWNW 19
#define M_    (NTOP*TOPW + NDOWN*DOWNW)   // 89670
#define SCALE_ 0.17677669529663687f       // 32^-0.5
#define BN_EPS 1e-5f

// ---------- bf16 helpers (raw u16 storage) ----------
__device__ __forceinline__ float b2f(u16 u) {
    union { uint32_t i; float f; } v; v.i = ((uint32_t)u) << 16; return v.f;
}
__device__ __forceinline__ u16 f2b(float f) {
    union { float f; uint32_t i; } v; v.f = f;
    uint32_t r = v.i + 0x7fffu + ((v.i >> 16) & 1u);   // RNE
    return (u16)(r >> 16);
}
// adaptive load: element i of a float tensor that is either f32 (isf32=1) or bf16
__device__ __forceinline__ float ld(const void* p, size_t i, int isf32) {
    return isf32 ? ((const float*)p)[i] : b2f(((const u16*)p)[i]);
}

// bijective XCD swizzle for grid=1281 (m204 formula; 1281 = 8*160 + 1)
__device__ __forceinline__ int xcd_swz_1281(int bx) {
    const int q = 160, r = 1;
    int xcd = bx & 7, o = bx >> 3;
    return (xcd < r ? xcd * (q + 1) : r * (q + 1) + (xcd - r) * q) + o;
}

// ---------- dtype probe: even u16 indices are garbage iff data is f32 ----------
__global__ void probe_k(const void* __restrict__ x, int* __restrict__ flag) {
    int lane = threadIdx.x;
    u16 v = ((const u16*)x)[2 * lane];
    int e = (v >> 7) & 0xff;
    bool ok = (e >= 118 && e <= 134);   // |val| in ~[2^-9, 2^8] -> plausible N(0,1) bf16
    unsigned long long m = __ballot(ok);
    if (lane == 0) *flag = (__popcll(m) < 32) ? 1 : 0;   // 1 = f32 inputs
}

// ---------- small prep kernels (dtype-adaptive) ----------
// Writes TRANSPOSED weights: WcatT[j][k] (1024x256), WprojT[j][k] (256x256)
__global__ void wcat_k(const void* __restrict__ Wqkv, const void* __restrict__ Wres,
                       const void* __restrict__ Wproj,
                       u16* __restrict__ WcatT, u16* __restrict__ WprojT,
                       const int* __restrict__ flag) {
    const int f = *flag;
    int k = blockIdx.x, t = threadIdx.x;
    for (int j = t; j < 768; j += 256) WcatT[(size_t)j * 256 + k] = f2b(ld(Wqkv, (size_t)k * 768 + j, f));
    WcatT[(size_t)(768 + t) * 256 + k] = f2b(ld(Wres, (size_t)k * 256 + t, f));
    WprojT[(size_t)t * 256 + k] = f2b(ld(Wproj, (size_t)k * 256 + t, f));
}

__global__ void biasprep_k(const void* bqkv, const void* bres, const void* bproj,
                           float* bias_cat, float* bias_proj, const int* __restrict__ flag) {
    const int f = *flag;
    int g = blockIdx.x * 256 + threadIdx.x;
    if (g < 768) bias_cat[g] = ld(bqkv, g, f);
    else if (g < 1024) bias_cat[g] = ld(bres, g - 768, f);
    else if (g < 1280) bias_proj[g - 1024] = ld(bproj, g - 1024, f);
}

// WfT[t][i] = (Wm1 @ Wm2)[i][t]   (transposed product), bf16 out
__global__ __launch_bounds__(256) void wf_k(const void* __restrict__ Wm1, const void* __restrict__ Wm2,
                                            u16* __restrict__ WfT, const int* __restrict__ flag) {
    const int f = *flag;
    __shared__ float row[512];
    int i = blockIdx.x, t = threadIdx.x;
    row[t] = ld(Wm1, (size_t)i * 512 + t, f);
    row[t + 256] = ld(Wm1, (size_t)i * 512 + 256 + t, f);
    __syncthreads();
    float acc = 0.f;
    for (int k = 0; k < 512; ++k) acc += row[k] * ld(Wm2, (size_t)k * 256 + t, f);
    WfT[(size_t)t * 256 + i] = f2b(acc);
}

// bf = bm1 @ Wm2 + bm2   (f32)
__global__ void bf_k(const void* bm1, const void* __restrict__ Wm2, const void* bm2,
                     float* bf, const int* __restrict__ flag) {
    const int f = *flag;
    int t = threadIdx.x;
    float acc = ld(bm2, t, f);
    for (int k = 0; k < 512; ++k) acc += ld(bm1, k, f) * ld(Wm2, (size_t)k * 256 + t, f);
    bf[t] = acc;
}

// ---------- QKV(+res) GEMM: A->LDS once (1 barrier), B register bursts ----------
// Grid (1281, 2): blockIdx.y selects a 512-col half -> 2x blocks for latency hiding.
// Out(BN x 1024) = X^T(BN x 256) @ Wcat(256 x 1024) + bias_cat
__global__ __launch_bounds__(256) void gemm_qkv_k(
    const void* __restrict__ x, const u16* __restrict__ WcatT,
    const float* __restrict__ bias, u16* __restrict__ Out, const int* __restrict__ flag)
{
    const int isf32 = *flag;
    __shared__ __align__(16) u16 As[64][264];
    const int tid = threadIdx.x;
    const int bx = xcd_swz_1281(blockIdx.x);
    const int R0 = bx * 64;
    const int CH0 = blockIdx.y * 512;     // column half base
    const int wave = tid >> 6, lane = tid & 63;
    const int quad = lane >> 4, mrow = lane & 15;

    // ---- stage A once into LDS ----
    const bool fastA = (R0 + 64 <= N_) || (R0 >= N_ && R0 + 64 <= BN_);
    if (fastA) {
        const int b = (R0 >= N_) ? 1 : 0;
        const int nn = R0 - b * N_;
        const int k = tid;
        if (isf32) {
            const float* xp = (const float*)x + (size_t)(b * 256 + k) * N_ + nn;
#pragma unroll
            for (int j = 0; j < 32; ++j) {
                float2 v = *reinterpret_cast<const float2*>(xp + 2 * j);
                As[2 * j][k] = f2b(v.x);
                As[2 * j + 1][k] = f2b(v.y);
            }
        } else {
            const u16* xp = (const u16*)x + (size_t)(b * 256 + k) * N_ + nn;
#pragma unroll
            for (int j = 0; j < 32; ++j) {
                uint32_t v = *reinterpret_cast<const uint32_t*>(xp + 2 * j);
                As[2 * j][k] = (u16)v;
                As[2 * j + 1][k] = (u16)(v >> 16);
            }
        }
    } else {
        const int n = tid & 63;
        const int kg = tid >> 6;
        const int g = R0 + n;
        const bool valid = (g < BN_);
        const int b = (g >= N_) ? 1 : 0;
        const int nn = g - b * N_;
#pragma unroll
        for (int j = 0; j < 8; ++j) {
            const int k0 = kg * 8 + j * 32;
            u16 tmp[8];
            if (valid) {
#pragma unroll
                for (int i = 0; i < 8; ++i) tmp[i] = f2b(ld(x, (size_t)(b * 256 + k0 + i) * N_ + nn, isf32));
            } else {
#pragma unroll
                for (int i = 0; i < 8; ++i) tmp[i] = 0;
            }
            *reinterpret_cast<uint4*>(&As[n][k0]) = *reinterpret_cast<const uint4*>(tmp);
        }
    }
    __syncthreads();   // the ONLY barrier

    for (int ct = 0; ct < 8; ++ct) {
        const int col = CH0 + ct * 64 + wave * 16 + mrow;
        const u16* bp = WcatT + (size_t)col * 256 + quad * 8;
        // explicit burst: all 8 B fragments into named registers BEFORE compute
        uint4 breg[8];
#pragma unroll
        for (int kc = 0; kc < 8; ++kc) breg[kc] = *reinterpret_cast<const uint4*>(bp + kc * 32);
        f32x4 acc[4] = {f32x4{0,0,0,0}, f32x4{0,0,0,0}, f32x4{0,0,0,0}, f32x4{0,0,0,0}};
#pragma unroll
        for (int kc = 0; kc < 8; ++kc) {
            bf16x8 bfrag = *reinterpret_cast<const bf16x8*>(&breg[kc]);
#pragma unroll
            for (int t2 = 0; t2 < 4; ++t2) {
                bf16x8 afrag = *reinterpret_cast<const bf16x8*>(&As[t2 * 16 + mrow][kc * 32 + quad * 8]);
                acc[t2] = __builtin_amdgcn_mfma_f32_16x16x32_bf16(afrag, bfrag, acc[t2], 0, 0, 0);
            }
        }
        const float bcol = bias[col];
#pragma unroll
        for (int t2 = 0; t2 < 4; ++t2) {
#pragma unroll
            for (int r = 0; r < 4; ++r) {
                int row = R0 + t2 * 16 + quad * 4 + r;
                if (row < BN_) {
                    Out[(size_t)row * 1024 + col] = f2b(acc[t2][r] + bcol);
                }
            }
        }
    }
}

// ---------- generic MFMA GEMM: A->LDS once (1 barrier), B via explicit register bursts ----------
// Out(Rtot x 256) = A(Rtot x 256, ldA) @ W(256 x 256) + bias;  Bt = W^T (256 x 256)
template<bool ADD_RES, bool OUT_F32>
__global__ __launch_bounds__(256) void gemm_k(
    const u16* __restrict__ A, int ldA, const u16* __restrict__ Bt,
    const float* __restrict__ bias,
    const u16* __restrict__ resp, int ldRes,
    void* __restrict__ Out, int ldOut, int Rtot)
{
    __shared__ __align__(16) u16 As[64][264];
    const int tid = threadIdx.x;
    const int bx = xcd_swz_1281(blockIdx.x);
    const int R0 = bx * 64;
    const int wave = tid >> 6, lane = tid & 63;
    const int quad = lane >> 4, mrow = lane & 15;

    // ---- stage A once: pure uint4 copies (A rows contiguous) ----
#pragma unroll
    for (int it = 0; it < 8; ++it) {
        int e = it * 256 + tid;
        int row = e >> 5, ks = (e & 31) * 8;
        uint4 v = make_uint4(0u, 0u, 0u, 0u);
        if (R0 + row < Rtot)
            v = *reinterpret_cast<const uint4*>(A + (size_t)(R0 + row) * ldA + ks);
        *reinterpret_cast<uint4*>(&As[row][ks]) = v;
    }
    __syncthreads();   // the ONLY barrier

    for (int ct = 0; ct < 4; ++ct) {
        const int col = ct * 64 + wave * 16 + mrow;
        const u16* bp = Bt + (size_t)col * 256 + quad * 8;
        uint4 breg[8];
#pragma unroll
        for (int kc = 0; kc < 8; ++kc) breg[kc] = *reinterpret_cast<const uint4*>(bp + kc * 32);
        f32x4 acc[4] = {f32x4{0,0,0,0}, f32x4{0,0,0,0}, f32x4{0,0,0,0}, f32x4{0,0,0,0}};
#pragma unroll
        for (int kc = 0; kc < 8; ++kc) {
            bf16x8 bfrag = *reinterpret_cast<const bf16x8*>(&breg[kc]);
#pragma unroll
            for (int t2 = 0; t2 < 4; ++t2) {
                bf16x8 afrag = *reinterpret_cast<const bf16x8*>(&As[t2 * 16 + mrow][kc * 32 + quad * 8]);
                acc[t2] = __builtin_amdgcn_mfma_f32_16x16x32_bf16(afrag, bfrag, acc[t2], 0, 0, 0);
            }
        }
        const float bcol = bias[col];
#pragma unroll
        for (int t2 = 0; t2 < 4; ++t2) {
#pragma unroll
            for (int r = 0; r < 4; ++r) {
                int row = R0 + t2 * 16 + quad * 4 + r;
                if (row < Rtot) {
                    float v = acc[t2][r] + bcol;
                    if (ADD_RES) v += b2f(resp[(size_t)row * ldRes + col]);
                    if (OUT_F32) ((float*)Out)[(size_t)row * ldOut + col] = v;
                    else         ((u16*)Out)[(size_t)row * ldOut + col] = f2b(v);
                }
            }
        }
    }
}

// ---------- window attention (one block = one window x one batch, all 8 heads) ----------
template<int W>
__global__ __launch_bounds__(256) void attn_k(const u16* __restrict__ qkv, const int* __restrict__ widx,
                                              u16* __restrict__ xw, int mbase)
{
    const int w = blockIdx.x, b = blockIdx.y;
    const int tid = threadIdx.x;
    __shared__ int wi[W];
    __shared__ __align__(16) float Ks[W][H_][36];
    __shared__ __align__(16) float Vs[W][H_][36];
    if (tid < W) wi[tid] = widx[w * W + tid];
    __syncthreads();
    for (int e = tid; e < W * 32; e += 256) {
        int j = e >> 5, seg = e & 31;
        size_t base = ((size_t)(b * N_ + wi[j])) * 1024 + 256 + seg * 8;
        uint4 kv = *reinterpret_cast<const uint4*>(qkv + base);         // K
        uint4 vv = *reinterpret_cast<const uint4*>(qkv + base + 256);   // V
        int h = seg >> 2, c0 = (seg & 3) * 8;
        const u16* kp = (const u16*)&kv; const u16* vp = (const u16*)&vv;
#pragma unroll
        for (int t = 0; t < 8; ++t) {
            Ks[j][h][c0 + t] = b2f(kp[t]);
            Vs[j][h][c0 + t] = b2f(vp[t]);
        }
    }
    __syncthreads();

    if (tid < W * H_) {
        const int j = tid >> 3, h = tid & 7;
        float qr[32];
        {
            size_t qb = ((size_t)(b * N_ + wi[j])) * 1024 + h * 32;
#pragma unroll
            for (int s4 = 0; s4 < 4; ++s4) {
                uint4 qv = *reinterpret_cast<const uint4*>(qkv + qb + s4 * 8);
                const u16* qp = (const u16*)&qv;
#pragma unroll
                for (int t = 0; t < 8; ++t) qr[s4 * 8 + t] = b2f(qp[t]) * SCALE_;
            }
        }
        float p[W];
        float mx = -1e30f;
#pragma unroll
        for (int jj = 0; jj < W; ++jj) {
            const float* kr = &Ks[jj][h][0];
            float s = 0.f;
#pragma unroll
            for (int c = 0; c < 32; ++c) s += qr[c] * kr[c];
            p[jj] = s;
            mx = fmaxf(mx, s);
        }
        float sum = 0.f;
#pragma unroll
        for (int jj = 0; jj < W; ++jj) { p[jj] = __expf(p[jj] - mx); sum += p[jj]; }
        const float inv = 1.0f / sum;
        float o[32];
#pragma unroll
        for (int c = 0; c < 32; ++c) o[c] = 0.f;
#pragma unroll
        for (int jj = 0; jj < W; ++jj) {
            const float pj = p[jj];
            const float* vr = &Vs[jj][h][0];
#pragma unroll
            for (int c = 0; c < 32; ++c) o[c] += pj * vr[c];
        }
        const int m = mbase + w * W + j;
        size_t off = ((size_t)b * (M_ + 1) + m) * 256 + h * 32;
#pragma unroll
        for (int s4 = 0; s4 < 4; ++s4) {
            uint32_t w0 = (uint32_t)f2b(o[s4 * 8 + 0] * inv) | ((uint32_t)f2b(o[s4 * 8 + 1] * inv) << 16);
            uint32_t w1 = (uint32_t)f2b(o[s4 * 8 + 2] * inv) | ((uint32_t)f2b(o[s4 * 8 + 3] * inv) << 16);
            uint32_t w2 = (uint32_t)f2b(o[s4 * 8 + 4] * inv) | ((uint32_t)f2b(o[s4 * 8 + 5] * inv) << 16);
            uint32_t w3 = (uint32_t)f2b(o[s4 * 8 + 6] * inv) | ((uint32_t)f2b(o[s4 * 8 + 7] * inv) << 16);
            *reinterpret_cast<uint4*>(xw + off + s4 * 8) = make_uint4(w0, w1, w2, w3);
        }
    }
}

// ---------- gather + average -> xf written into qkvres cols 0..255 (ld 1024) ----------
__global__ __launch_bounds__(256) void gather_k(const u16* __restrict__ xw, const int* __restrict__ rev,
                                                const void* __restrict__ cnt_inv, u16* __restrict__ xfp,
                                                int K, const int* __restrict__ flag)
{
    const int f = *flag;
    int gid = blockIdx.x * 4 + (threadIdx.x >> 6);
    if (gid >= BN_) return;
    int b = (gid >= N_) ? 1 : 0;
    int n = gid - b * N_;
    int c4 = (threadIdx.x & 63) * 4;
    float a0 = 0, a1 = 0, a2 = 0, a3 = 0;
    const int* rp = rev + (size_t)n * K;
    for (int k = 0; k < K; ++k) {
        int idx = rp[k];
        if (idx < M_) {
            ushort4 v = *reinterpret_cast<const ushort4*>(xw + ((size_t)b * (M_ + 1) + idx) * 256 + c4);
            a0 += b2f(v.x); a1 += b2f(v.y); a2 += b2f(v.z); a3 += b2f(v.w);
        }
    }
    float ci = ld(cnt_inv, n, f);
    ushort4 o;
    o.x = f2b(a0 * ci); o.y = f2b(a1 * ci); o.z = f2b(a2 * ci); o.w = f2b(a3 * ci);
    *reinterpret_cast<ushort4*>(xfp + (size_t)gid * 1024 + c4) = o;
}

// ---------- BN stats over res2 (BN_ x 256 f32): per-column sum & sumsq ----------
#define STATS_BLOCKS 512
__global__ __launch_bounds__(256) void stats_k(const float* __restrict__ res2, float* __restrict__ sums) {
    const int tid = threadIdx.x;
    const int c4 = (tid & 63) * 4;    // column group
    const int rsub = tid >> 6;        // 0..3 (which row of the 4-row slab)
    float s[4] = {0.f, 0.f, 0.f, 0.f};
    float q[4] = {0.f, 0.f, 0.f, 0.f};
    for (int r = blockIdx.x * 4 + rsub; r < BN_; r += STATS_BLOCKS * 4) {
        float4 v = *reinterpret_cast<const float4*>(res2 + (size_t)r * 256 + c4);
        s[0] += v.x; q[0] += v.x * v.x;
        s[1] += v.y; q[1] += v.y * v.y;
        s[2] += v.z; q[2] += v.z * v.z;
        s[3] += v.w; q[3] += v.w * v.w;
    }
    __shared__ float rs[256][4];
    __shared__ float rq[256][4];
#pragma unroll
    for (int j = 0; j < 4; ++j) { rs[tid][j] = s[j]; rq[tid][j] = q[j]; }
    __syncthreads();
    if (tid < 64) {
#pragma unroll
        for (int j = 0; j < 4; ++j) {
            float a = rs[tid][j] + rs[tid + 64][j] + rs[tid + 128][j] + rs[tid + 192][j];
            float b = rq[tid][j] + rq[tid + 64][j] + rq[tid + 128][j] + rq[tid + 192][j];
            atomicAdd(&sums[c4 + j], a);
            atomicAdd(&sums[256 + c4 + j], b);
        }
    }
}

__global__ void bnfin_k(const float* sums, const void* gamma, const void* beta, float* ss,
                        const int* __restrict__ flag) {
    const int f = *flag;
    int c = threadIdx.x;
    float mean = sums[c] * (1.0f / BN_);
    float var = sums[256 + c] * (1.0f / BN_) - mean * mean;
    float inv = rsqrtf(fmaxf(var, 0.f) + BN_EPS);
    float sc = ld(gamma, c, f) * inv;
    ss[c] = sc;
    ss[256 + c] = ld(beta, c, f) - mean * sc;
}

// ---------- final: y[b,oc,n] = out[b,n,oc] + res2[b,n,oc]*scale[oc] + shift[oc] ----------
__global__ __launch_bounds__(256) void final_k(const u16* __restrict__ outb, const float* __restrict__ res2,
                                               const float* __restrict__ ss, void* __restrict__ y,
                                               const int* __restrict__ flag)
{
    const int isf32 = *flag;
    __shared__ __align__(16) float tile[64][65];
    const int n0 = blockIdx.x * 64, o0 = blockIdx.y * 64, b = blockIdx.z;
    const int tid = threadIdx.x;
    {
        const int ln = tid >> 2, os = (tid & 3) * 16;
        int n = n0 + ln;
        if (n < N_) {
            size_t base = ((size_t)(b * N_ + n)) * 256 + o0 + os;
            uint4 ov0 = *reinterpret_cast<const uint4*>(outb + base);
            uint4 ov1 = *reinterpret_cast<const uint4*>(outb + base + 8);
            const u16* op = (const u16*)&ov0;
            const u16* op1 = (const u16*)&ov1;
            float4 rv[4];
#pragma unroll
            for (int q = 0; q < 4; ++q) rv[q] = *reinterpret_cast<const float4*>(res2 + base + q * 4);
            const float* rp = (const float*)&rv[0];
#pragma unroll
            for (int j = 0; j < 16; ++j) {
                int oc = o0 + os + j;
                float ob = (j < 8) ? b2f(op[j]) : b2f(op1[j - 8]);
                tile[ln][os + j] = ob + rp[j] * ss[oc] + ss[256 + oc];
            }
        }
    }
    __syncthreads();
    {
        const int wave = tid >> 6, lane = tid & 63;
        int n = n0 + lane;
        if (n < N_) {
            if (isf32) {
                float* yp = (float*)y;
#pragma unroll
                for (int r0 = 0; r0 < 64; r0 += 4) {
                    int r = r0 + wave;
                    int oc = o0 + r;
                    yp[((size_t)(b * 256 + oc)) * N_ + n] = tile[lane][r];
                }
            } else {
                u16* yp = (u16*)y;
#pragma unroll
                for (int r0 = 0; r0 < 64; r0 += 4) {
                    int r = r0 + wave;
                    int oc = o0 + r;
                    yp[((size_t)(b * 256 + oc)) * N_ + n] = f2b(tile[lane][r]);
                }
            }
        }
    }
}

// ---------- workspace layout (bytes) ----------
static const size_t OFF_QKV   = 0;
static const size_t OFF_XW    = 167780352;
static const size_t OFF_SMALL = 259603456;

extern "C" void kernel_launch(void* const* d_in, const int* in_sizes, int n_in,
                              void* d_out, int out_size, void* d_ws, size_t ws_size,
                              hipStream_t stream) {
    const void* x     = d_in[0];
    const void* Wqkv  = d_in[1];
    const void* bqkv  = d_in[2];
    const void* Wproj = d_in[3];
    const void* bproj = d_in[4];
    const void* Wres  = d_in[5];
    const void* bres  = d_in[6];
    const void* Wm1   = d_in[7];
    const void* bm1   = d_in[8];
    const void* Wm2   = d_in[9];
    const void* bm2   = d_in[10];
    const void* gamma = d_in[11];
    const void* beta  = d_in[12];
    const void* cnt_inv = d_in[13];
    const int* top_idx = (const int*)d_in[14];
    const int* down_idx = (const int*)d_in[15];
    const int* rev   = (const int*)d_in[16];
    const int K = in_sizes[16] / N_;

    char* ws = (char*)d_ws;
    u16*  qkvres  = (u16*)(ws + OFF_QKV);
    float* res2   = (float*)(ws + OFF_QKV);
    u16*  xw      = (u16*)(ws + OFF_XW);
    u16*  outb    = (u16*)(ws + OFF_XW);
    u16*  WcatT   = (u16*)(ws + OFF_SMALL);
    u16*  WfT     = (u16*)(ws + OFF_SMALL + 524288);
    float* bias_cat  = (float*)(ws + OFF_SMALL + 655360);
    float* bias_proj = (float*)(ws + OFF_SMALL + 659456);
    float* bfv       = (float*)(ws + OFF_SMALL + 663552);
    float* stats     = (float*)(ws + OFF_SMALL + 667648);
    float* ssbuf     = (float*)(ws + OFF_SMALL + 671744);
    int*   flag      = (int*)(ws + OFF_SMALL + 675840);
    u16*  WprojT     = (u16*)(ws + OFF_SMALL + 679936);   // 131072 bytes

    // dtype probe first
    probe_k<<<1, 64, 0, stream>>>(x, flag);

    // prep (dtype-adaptive, transposed weights)
    wcat_k<<<256, 256, 0, stream>>>(Wqkv, Wres, Wproj, WcatT, WprojT, flag);
    biasprep_k<<<5, 256, 0, stream>>>(bqkv, bres, bproj, bias_cat, bias_proj, flag);
    wf_k<<<256, 256, 0, stream>>>(Wm1, Wm2, WfT, flag);
    bf_k<<<1, 256, 0, stream>>>(bm1, Wm2, bm2, bfv, flag);

    // qkv + res fused GEMM straight from x: (BN,256) @ (256,1024), col-split x2
    gemm_qkv_k<<<dim3(1281, 2), 256, 0, stream>>>(x, WcatT, bias_cat, qkvres, flag);

    // window attention: one block per (window, batch), all heads
    attn_k<TOPW><<<dim3(NTOP, B_), 256, 0, stream>>>(qkvres, top_idx, xw, 0);
    attn_k<DOWNW><<<dim3(NDOWN, B_), 256, 0, stream>>>(qkvres, down_idx, xw, NTOP * TOPW);

    // scatter-average back to points -> xf = qkvres cols 0..255 (q is dead)
    gather_k<<<(BN_ + 3) / 4, 256, 0, stream>>>(xw, rev, cnt_inv, qkvres, K, flag);

    // out = xf @ Wproj + bproj + res   (xf ldA=1024, res = qkvres cols 768..1023)
    gemm_k<true, false><<<1281, 256, 0, stream>>>(
        qkvres, 1024, WprojT, bias_proj, qkvres + 768, 1024, (void*)outb, 256, BN_);

    // res2 = out @ (Wm1@Wm2) + (bm1@Wm2+bm2)   (f32, overwrites dead qkvres front)
    gemm_k<false, true><<<1281, 256, 0, stream>>>(
        outb, 256, WfT, bfv, nullptr, 0, (void*)res2, 256, BN_);

    // batchnorm stats + finalize
    (void)hipMemsetAsync(stats, 0, 512 * sizeof(float), stream);
    stats_k<<<STATS_BLOCKS, 256, 0, stream>>>(res2, stats);
    bnfin_k<<<1, 256, 0, stream>>>(stats, gamma, beta, ssbuf, flag);

    // fused transpose + BN + residual add -> y (B, 256, N), dtype per flag
    final_k<<<dim3(641, 4, 2), 256, 0, stream>>>(outb, res2, ssbuf, d_out, flag);
}

// Round 13
// 855.549 us; speedup vs baseline: 1.1477x; 1.1125x over previous
//
#include <hip/hip_runtime.h>
#include <stdint.h>

typedef unsigned short u16;
typedef __bf16 bf16x8 __attribute__((ext_vector_type(8)));
typedef float f32x4 __attribute__((ext_vector_type(4)));

#define B_    2
#define C_    256
#define N_    40962
#define BN_   (B_ * N_)          // 81924
#define H_    8
#define HD_   32
#define NTOP  2562
#define TOPW  16
#define NDOWN 2562
#define DOWNW 19
#define M_    (NTOP*TOPW + NDOWN*DOWNW)   // 89670
#define SCALE_ 0.17677669529663687f       // 32^-0.5
#define BN_EPS 1e-5f

// ---------- bf16 helpers (raw u16 storage) ----------
__device__ __forceinline__ float b2f(u16 u) {
    union { uint32_t i; float f; } v; v.i = ((uint32_t)u) << 16; return v.f;
}
__device__ __forceinline__ u16 f2b(float f) {
    union { float f; uint32_t i; } v; v.f = f;
    uint32_t r = v.i + 0x7fffu + ((v.i >> 16) & 1u);   // RNE
    return (u16)(r >> 16);
}
// adaptive load: element i of a float tensor that is either f32 (isf32=1) or bf16
__device__ __forceinline__ float ld(const void* p, size_t i, int isf32) {
    return isf32 ? ((const float*)p)[i] : b2f(((const u16*)p)[i]);
}

// bijective XCD swizzle for grid=1281 (m204 formula; 1281 = 8*160 + 1)
__device__ __forceinline__ int xcd_swz_1281(int bx) {
    const int q = 160, r = 1;
    int xcd = bx & 7, o = bx >> 3;
    return (xcd < r ? xcd * (q + 1) : r * (q + 1) + (xcd - r) * q) + o;
}

// ---------- dtype probe: even u16 indices are garbage iff data is f32 ----------
__global__ void probe_k(const void* __restrict__ x, int* __restrict__ flag) {
    int lane = threadIdx.x;
    u16 v = ((const u16*)x)[2 * lane];
    int e = (v >> 7) & 0xff;
    bool ok = (e >= 118 && e <= 134);   // |val| in ~[2^-9, 2^8] -> plausible N(0,1) bf16
    unsigned long long m = __ballot(ok);
    if (lane == 0) *flag = (__popcll(m) < 32) ? 1 : 0;   // 1 = f32 inputs
}

// ---------- small prep kernels (dtype-adaptive) ----------
// Writes TRANSPOSED weights: WcatT[j][k] (1024x256), WprojT[j][k] (256x256)
__global__ void wcat_k(const void* __restrict__ Wqkv, const void* __restrict__ Wres,
                       const void* __restrict__ Wproj,
                       u16* __restrict__ WcatT, u16* __restrict__ WprojT,
                       const int* __restrict__ flag) {
    const int f = *flag;
    int k = blockIdx.x, t = threadIdx.x;
    for (int j = t; j < 768; j += 256) WcatT[(size_t)j * 256 + k] = f2b(ld(Wqkv, (size_t)k * 768 + j, f));
    WcatT[(size_t)(768 + t) * 256 + k] = f2b(ld(Wres, (size_t)k * 256 + t, f));
    WprojT[(size_t)t * 256 + k] = f2b(ld(Wproj, (size_t)k * 256 + t, f));
}

__global__ void biasprep_k(const void* bqkv, const void* bres, const void* bproj,
                           float* bias_cat, float* bias_proj, const int* __restrict__ flag) {
    const int f = *flag;
    int g = blockIdx.x * 256 + threadIdx.x;
    if (g < 768) bias_cat[g] = ld(bqkv, g, f);
    else if (g < 1024) bias_cat[g] = ld(bres, g - 768, f);
    else if (g < 1280) bias_proj[g - 1024] = ld(bproj, g - 1024, f);
}

// WfT[t][i] = (Wm1 @ Wm2)[i][t]   (transposed product), bf16 out
__global__ __launch_bounds__(256) void wf_k(const void* __restrict__ Wm1, const void* __restrict__ Wm2,
                                            u16* __restrict__ WfT, const int* __restrict__ flag) {
    const int f = *flag;
    __shared__ float row[512];
    int i = blockIdx.x, t = threadIdx.x;
    row[t] = ld(Wm1, (size_t)i * 512 + t, f);
    row[t + 256] = ld(Wm1, (size_t)i * 512 + 256 + t, f);
    __syncthreads();
    float acc = 0.f;
    for (int k = 0; k < 512; ++k) acc += row[k] * ld(Wm2, (size_t)k * 256 + t, f);
    WfT[(size_t)t * 256 + i] = f2b(acc);
}

// bf = bm1 @ Wm2 + bm2   (f32)
__global__ void bf_k(const void* bm1, const void* __restrict__ Wm2, const void* bm2,
                     float* bf, const int* __restrict__ flag) {
    const int f = *flag;
    int t = threadIdx.x;
    float acc = ld(bm2, t, f);
    for (int k = 0; k < 512; ++k) acc += ld(bm1, k, f) * ld(Wm2, (size_t)k * 256 + t, f);
    bf[t] = acc;
}

// ---------- QKV(+res) GEMM: A->LDS once, B register bursts, LDS-staged coalesced stores ----------
// Out(BN x 1024) = X^T(BN x 256) @ Wcat(256 x 1024) + bias_cat
__global__ __launch_bounds__(256) void gemm_qkv_k(
    const void* __restrict__ x, const u16* __restrict__ WcatT,
    const float* __restrict__ bias, u16* __restrict__ Out, const int* __restrict__ flag)
{
    const int isf32 = *flag;
    __shared__ __align__(16) u16 As[64][264];
    __shared__ __align__(16) u16 Ot[64][72];   // out-tile staging (row stride 144B, 16B-aligned)
    const int tid = threadIdx.x;
    const int bx = xcd_swz_1281(blockIdx.x);
    const int R0 = bx * 64;
    const int wave = tid >> 6, lane = tid & 63;
    const int quad = lane >> 4, mrow = lane & 15;
    const int srow = tid >> 2, schunk = (tid & 3) * 16;   // store-phase mapping

    // ---- stage A once into LDS ----
    const bool fastA = (R0 + 64 <= N_) || (R0 >= N_ && R0 + 64 <= BN_);
    if (fastA) {
        const int b = (R0 >= N_) ? 1 : 0;
        const int nn = R0 - b * N_;
        const int k = tid;
        if (isf32) {
            const float* xp = (const float*)x + (size_t)(b * 256 + k) * N_ + nn;
#pragma unroll
            for (int j = 0; j < 32; ++j) {
                float2 v = *reinterpret_cast<const float2*>(xp + 2 * j);
                As[2 * j][k] = f2b(v.x);
                As[2 * j + 1][k] = f2b(v.y);
            }
        } else {
            const u16* xp = (const u16*)x + (size_t)(b * 256 + k) * N_ + nn;
#pragma unroll
            for (int j = 0; j < 32; ++j) {
                uint32_t v = *reinterpret_cast<const uint32_t*>(xp + 2 * j);
                As[2 * j][k] = (u16)v;
                As[2 * j + 1][k] = (u16)(v >> 16);
            }
        }
    } else {
        const int n = tid & 63;
        const int kg = tid >> 6;
        const int g = R0 + n;
        const bool valid = (g < BN_);
        const int b = (g >= N_) ? 1 : 0;
        const int nn = g - b * N_;
#pragma unroll
        for (int j = 0; j < 8; ++j) {
            const int k0 = kg * 8 + j * 32;
            u16 tmp[8];
            if (valid) {
#pragma unroll
                for (int i = 0; i < 8; ++i) tmp[i] = f2b(ld(x, (size_t)(b * 256 + k0 + i) * N_ + nn, isf32));
            } else {
#pragma unroll
                for (int i = 0; i < 8; ++i) tmp[i] = 0;
            }
            *reinterpret_cast<uint4*>(&As[n][k0]) = *reinterpret_cast<const uint4*>(tmp);
        }
    }
    __syncthreads();   // As ready

    const bool rowOK = (R0 + 64 <= BN_);   // whole tile in range? (boundary block handles guards)

    for (int ct = 0; ct < 16; ++ct) {
        const int col = ct * 64 + wave * 16 + mrow;
        const u16* bp = WcatT + (size_t)col * 256 + quad * 8;
        // explicit burst: all 8 B fragments into named registers BEFORE compute
        uint4 breg[8];
#pragma unroll
        for (int kc = 0; kc < 8; ++kc) breg[kc] = *reinterpret_cast<const uint4*>(bp + kc * 32);
        f32x4 acc[4] = {f32x4{0,0,0,0}, f32x4{0,0,0,0}, f32x4{0,0,0,0}, f32x4{0,0,0,0}};
#pragma unroll
        for (int kc = 0; kc < 8; ++kc) {
            bf16x8 bfrag = *reinterpret_cast<const bf16x8*>(&breg[kc]);
#pragma unroll
            for (int t2 = 0; t2 < 4; ++t2) {
                bf16x8 afrag = *reinterpret_cast<const bf16x8*>(&As[t2 * 16 + mrow][kc * 32 + quad * 8]);
                acc[t2] = __builtin_amdgcn_mfma_f32_16x16x32_bf16(afrag, bfrag, acc[t2], 0, 0, 0);
            }
        }
        const float bcol = bias[col];
        __syncthreads();   // Ot free (previous tile's store-phase reads done)
#pragma unroll
        for (int t2 = 0; t2 < 4; ++t2) {
#pragma unroll
            for (int r = 0; r < 4; ++r) {
                Ot[t2 * 16 + quad * 4 + r][wave * 16 + mrow] = f2b(acc[t2][r] + bcol);
            }
        }
        __syncthreads();   // Ot ready
        // coalesced store: each thread writes 32B of one row (2x uint4)
        if (rowOK || (R0 + srow < BN_)) {
            const size_t ob = (size_t)(R0 + srow) * 1024 + ct * 64 + schunk;
            *reinterpret_cast<uint4*>(Out + ob)     = *reinterpret_cast<const uint4*>(&Ot[srow][schunk]);
            *reinterpret_cast<uint4*>(Out + ob + 8) = *reinterpret_cast<const uint4*>(&Ot[srow][schunk + 8]);
        }
    }
}

// ---------- generic MFMA GEMM: A->LDS once (1 barrier), B via explicit register bursts ----------
// Out(Rtot x 256) = A(Rtot x 256, ldA) @ W(256 x 256) + bias;  Bt = W^T (256 x 256)
template<bool ADD_RES, bool OUT_F32>
__global__ __launch_bounds__(256) void gemm_k(
    const u16* __restrict__ A, int ldA, const u16* __restrict__ Bt,
    const float* __restrict__ bias,
    const u16* __restrict__ resp, int ldRes,
    void* __restrict__ Out, int ldOut, int Rtot)
{
    __shared__ __align__(16) u16 As[64][264];
    const int tid = threadIdx.x;
    const int bx = xcd_swz_1281(blockIdx.x);
    const int R0 = bx * 64;
    const int wave = tid >> 6, lane = tid & 63;
    const int quad = lane >> 4, mrow = lane & 15;

    // ---- stage A once: pure uint4 copies (A rows contiguous) ----
#pragma unroll
    for (int it = 0; it < 8; ++it) {
        int e = it * 256 + tid;
        int row = e >> 5, ks = (e & 31) * 8;
        uint4 v = make_uint4(0u, 0u, 0u, 0u);
        if (R0 + row < Rtot)
            v = *reinterpret_cast<const uint4*>(A + (size_t)(R0 + row) * ldA + ks);
        *reinterpret_cast<uint4*>(&As[row][ks]) = v;
    }
    __syncthreads();   // the ONLY barrier

    for (int ct = 0; ct < 4; ++ct) {
        const int col = ct * 64 + wave * 16 + mrow;
        const u16* bp = Bt + (size_t)col * 256 + quad * 8;
        uint4 breg[8];
#pragma unroll
        for (int kc = 0; kc < 8; ++kc) breg[kc] = *reinterpret_cast<const uint4*>(bp + kc * 32);
        f32x4 acc[4] = {f32x4{0,0,0,0}, f32x4{0,0,0,0}, f32x4{0,0,0,0}, f32x4{0,0,0,0}};
#pragma unroll
        for (int kc = 0; kc < 8; ++kc) {
            bf16x8 bfrag = *reinterpret_cast<const bf16x8*>(&breg[kc]);
#pragma unroll
            for (int t2 = 0; t2 < 4; ++t2) {
                bf16x8 afrag = *reinterpret_cast<const bf16x8*>(&As[t2 * 16 + mrow][kc * 32 + quad * 8]);
                acc[t2] = __builtin_amdgcn_mfma_f32_16x16x32_bf16(afrag, bfrag, acc[t2], 0, 0, 0);
            }
        }
        const float bcol = bias[col];
#pragma unroll
        for (int t2 = 0; t2 < 4; ++t2) {
#pragma unroll
            for (int r = 0; r < 4; ++r) {
                int row = R0 + t2 * 16 + quad * 4 + r;
                if (row < Rtot) {
                    float v = acc[t2][r] + bcol;
                    if (ADD_RES) v += b2f(resp[(size_t)row * ldRes + col]);
                    if (OUT_F32) ((float*)Out)[(size_t)row * ldOut + col] = v;
                    else         ((u16*)Out)[(size_t)row * ldOut + col] = f2b(v);
                }
            }
        }
    }
}

// ---------- window attention (one block = one window x one batch, all 8 heads) ----------
template<int W>
__global__ __launch_bounds__(256) void attn_k(const u16* __restrict__ qkv, const int* __restrict__ widx,
                                              u16* __restrict__ xw, int mbase)
{
    const int w = blockIdx.x, b = blockIdx.y;
    const int tid = threadIdx.x;
    __shared__ int wi[W];
    __shared__ __align__(16) float Ks[W][H_][36];
    __shared__ __align__(16) float Vs[W][H_][36];
    if (tid < W) wi[tid] = widx[w * W + tid];
    __syncthreads();
    for (int e = tid; e < W * 32; e += 256) {
        int j = e >> 5, seg = e & 31;
        size_t base = ((size_t)(b * N_ + wi[j])) * 1024 + 256 + seg * 8;
        uint4 kv = *reinterpret_cast<const uint4*>(qkv + base);         // K
        uint4 vv = *reinterpret_cast<const uint4*>(qkv + base + 256);   // V
        int h = seg >> 2, c0 = (seg & 3) * 8;
        const u16* kp = (const u16*)&kv; const u16* vp = (const u16*)&vv;
#pragma unroll
        for (int t = 0; t < 8; ++t) {
            Ks[j][h][c0 + t] = b2f(kp[t]);
            Vs[j][h][c0 + t] = b2f(vp[t]);
        }
    }
    __syncthreads();

    if (tid < W * H_) {
        const int j = tid >> 3, h = tid & 7;
        float qr[32];
        {
            size_t qb = ((size_t)(b * N_ + wi[j])) * 1024 + h * 32;
#pragma unroll
            for (int s4 = 0; s4 < 4; ++s4) {
                uint4 qv = *reinterpret_cast<const uint4*>(qkv + qb + s4 * 8);
                const u16* qp = (const u16*)&qv;
#pragma unroll
                for (int t = 0; t < 8; ++t) qr[s4 * 8 + t] = b2f(qp[t]) * SCALE_;
            }
        }
        float p[W];
        float mx = -1e30f;
#pragma unroll
        for (int jj = 0; jj < W; ++jj) {
            const float* kr = &Ks[jj][h][0];
            float s = 0.f;
#pragma unroll
            for (int c = 0; c < 32; ++c) s += qr[c] * kr[c];
            p[jj] = s;
            mx = fmaxf(mx, s);
        }
        float sum = 0.f;
#pragma unroll
        for (int jj = 0; jj < W; ++jj) { p[jj] = __expf(p[jj] - mx); sum += p[jj]; }
        const float inv = 1.0f / sum;
        float o[32];
#pragma unroll
        for (int c = 0; c < 32; ++c) o[c] = 0.f;
#pragma unroll
        for (int jj = 0; jj < W; ++jj) {
            const float pj = p[jj];
            const float* vr = &Vs[jj][h][0];
#pragma unroll
            for (int c = 0; c < 32; ++c) o[c] += pj * vr[c];
        }
        const int m = mbase + w * W + j;
        size_t off = ((size_t)b * (M_ + 1) + m) * 256 + h * 32;
#pragma unroll
        for (int s4 = 0; s4 < 4; ++s4) {
            uint32_t w0 = (uint32_t)f2b(o[s4 * 8 + 0] * inv) | ((uint32_t)f2b(o[s4 * 8 + 1] * inv) << 16);
            uint32_t w1 = (uint32_t)f2b(o[s4 * 8 + 2] * inv) | ((uint32_t)f2b(o[s4 * 8 + 3] * inv) << 16);
            uint32_t w2 = (uint32_t)f2b(o[s4 * 8 + 4] * inv) | ((uint32_t)f2b(o[s4 * 8 + 5] * inv) << 16);
            uint32_t w3 = (uint32_t)f2b(o[s4 * 8 + 6] * inv) | ((uint32_t)f2b(o[s4 * 8 + 7] * inv) << 16);
            *reinterpret_cast<uint4*>(xw + off + s4 * 8) = make_uint4(w0, w1, w2, w3);
        }
    }
}

// ---------- gather + average -> xf written into qkvres cols 0..255 (ld 1024) ----------
__global__ __launch_bounds__(256) void gather_k(const u16* __restrict__ xw, const int* __restrict__ rev,
                                                const void* __restrict__ cnt_inv, u16* __restrict__ xfp,
                                                int K, const int* __restrict__ flag)
{
    const int f = *flag;
    int gid = blockIdx.x * 4 + (threadIdx.x >> 6);
    if (gid >= BN_) return;
    int b = (gid >= N_) ? 1 : 0;
    int n = gid - b * N_;
    int c4 = (threadIdx.x & 63) * 4;
    float a0 = 0, a1 = 0, a2 = 0, a3 = 0;
    const int* rp = rev + (size_t)n * K;
    for (int k = 0; k < K; ++k) {
        int idx = rp[k];
        if (idx < M_) {
            ushort4 v = *reinterpret_cast<const ushort4*>(xw + ((size_t)b * (M_ + 1) + idx) * 256 + c4);
            a0 += b2f(v.x); a1 += b2f(v.y); a2 += b2f(v.z); a3 += b2f(v.w);
        }
    }
    float ci = ld(cnt_inv, n, f);
    ushort4 o;
    o.x = f2b(a0 * ci); o.y = f2b(a1 * ci); o.z = f2b(a2 * ci); o.w = f2b(a3 * ci);
    *reinterpret_cast<ushort4*>(xfp + (size_t)gid * 1024 + c4) = o;
}

// ---------- BN stats over res2 (BN_ x 256 f32): per-column sum & sumsq ----------
#define STATS_BLOCKS 512
__global__ __launch_bounds__(256) void stats_k(const float* __restrict__ res2, float* __restrict__ sums) {
    const int tid = threadIdx.x;
    const int c4 = (tid & 63) * 4;    // column group
    const int rsub = tid >> 6;        // 0..3 (which row of the 4-row slab)
    float s[4] = {0.f, 0.f, 0.f, 0.f};
    float q[4] = {0.f, 0.f, 0.f, 0.f};
    for (int r = blockIdx.x * 4 + rsub; r < BN_; r += STATS_BLOCKS * 4) {
        float4 v = *reinterpret_cast<const float4*>(res2 + (size_t)r * 256 + c4);
        s[0] += v.x; q[0] += v.x * v.x;
        s[1] += v.y; q[1] += v.y * v.y;
        s[2] += v.z; q[2] += v.z * v.z;
        s[3] += v.w; q[3] += v.w * v.w;
    }
    __shared__ float rs[256][4];
    __shared__ float rq[256][4];
#pragma unroll
    for (int j = 0; j < 4; ++j) { rs[tid][j] = s[j]; rq[tid][j] = q[j]; }
    __syncthreads();
    if (tid < 64) {
#pragma unroll
        for (int j = 0; j < 4; ++j) {
            float a = rs[tid][j] + rs[tid + 64][j] + rs[tid + 128][j] + rs[tid + 192][j];
            float b = rq[tid][j] + rq[tid + 64][j] + rq[tid + 128][j] + rq[tid + 192][j];
            atomicAdd(&sums[c4 + j], a);
            atomicAdd(&sums[256 + c4 + j], b);
        }
    }
}

__global__ void bnfin_k(const float* sums, const void* gamma, const void* beta, float* ss,
                        const int* __restrict__ flag) {
    const int f = *flag;
    int c = threadIdx.x;
    float mean = sums[c] * (1.0f / BN_);
    float var = sums[256 + c] * (1.0f / BN_) - mean * mean;
    float inv = rsqrtf(fmaxf(var, 0.f) + BN_EPS);
    float sc = ld(gamma, c, f) * inv;
    ss[c] = sc;
    ss[256 + c] = ld(beta, c, f) - mean * sc;
}

// ---------- final: y[b,oc,n] = out[b,n,oc] + res2[b,n,oc]*scale[oc] + shift[oc] ----------
__global__ __launch_bounds__(256) void final_k(const u16* __restrict__ outb, const float* __restrict__ res2,
                                               const float* __restrict__ ss, void* __restrict__ y,
                                               const int* __restrict__ flag)
{
    const int isf32 = *flag;
    __shared__ __align__(16) float tile[64][65];
    const int n0 = blockIdx.x * 64, o0 = blockIdx.y * 64, b = blockIdx.z;
    const int tid = threadIdx.x;
    {
        const int ln = tid >> 2, os = (tid & 3) * 16;
        int n = n0 + ln;
        if (n < N_) {
            size_t base = ((size_t)(b * N_ + n)) * 256 + o0 + os;
            uint4 ov0 = *reinterpret_cast<const uint4*>(outb + base);
            uint4 ov1 = *reinterpret_cast<const uint4*>(outb + base + 8);
            const u16* op = (const u16*)&ov0;
            const u16* op1 = (const u16*)&ov1;
            float4 rv[4];
#pragma unroll
            for (int q = 0; q < 4; ++q) rv[q] = *reinterpret_cast<const float4*>(res2 + base + q * 4);
            const float* rp = (const float*)&rv[0];
#pragma unroll
            for (int j = 0; j < 16; ++j) {
                int oc = o0 + os + j;
                float ob = (j < 8) ? b2f(op[j]) : b2f(op1[j - 8]);
                tile[ln][os + j] = ob + rp[j] * ss[oc] + ss[256 + oc];
            }
        }
    }
    __syncthreads();
    {
        const int wave = tid >> 6, lane = tid & 63;
        int n = n0 + lane;
        if (n < N_) {
            if (isf32) {
                float* yp = (float*)y;
#pragma unroll
                for (int r0 = 0; r0 < 64; r0 += 4) {
                    int r = r0 + wave;
                    int oc = o0 + r;
                    yp[((size_t)(b * 256 + oc)) * N_ + n] = tile[lane][r];
                }
            } else {
                u16* yp = (u16*)y;
#pragma unroll
                for (int r0 = 0; r0 < 64; r0 += 4) {
                    int r = r0 + wave;
                    int oc = o0 + r;
                    yp[((size_t)(b * 256 + oc)) * N_ + n] = f2b(tile[lane][r]);
                }
            }
        }
    }
}

// ---------- workspace layout (bytes) ----------
static const size_t OFF_QKV   = 0;
static const size_t OFF_XW    = 167780352;
static const size_t OFF_SMALL = 259603456;

extern "C" void kernel_launch(void* const* d_in, const int* in_sizes, int n_in,
                              void* d_out, int out_size, void* d_ws, size_t ws_size,
                              hipStream_t stream) {
    const void* x     = d_in[0];
    const void* Wqkv  = d_in[1];
    const void* bqkv  = d_in[2];
    const void* Wproj = d_in[3];
    const void* bproj = d_in[4];
    const void* Wres  = d_in[5];
    const void* bres  = d_in[6];
    const void* Wm1   = d_in[7];
    const void* bm1   = d_in[8];
    const void* Wm2   = d_in[9];
    const void* bm2   = d_in[10];
    const void* gamma = d_in[11];
    const void* beta  = d_in[12];
    const void* cnt_inv = d_in[13];
    const int* top_idx = (const int*)d_in[14];
    const int* down_idx = (const int*)d_in[15];
    const int* rev   = (const int*)d_in[16];
    const int K = in_sizes[16] / N_;

    char* ws = (char*)d_ws;
    u16*  qkvres  = (u16*)(ws + OFF_QKV);
    float* res2   = (float*)(ws + OFF_QKV);
    u16*  xw      = (u16*)(ws + OFF_XW);
    u16*  outb    = (u16*)(ws + OFF_XW);
    u16*  WcatT   = (u16*)(ws + OFF_SMALL);
    u16*  WfT     = (u16*)(ws + OFF_SMALL + 524288);
    float* bias_cat  = (float*)(ws + OFF_SMALL + 655360);
    float* bias_proj = (float*)(ws + OFF_SMALL + 659456);
    float* bfv       = (float*)(ws + OFF_SMALL + 663552);
    float* stats     = (float*)(ws + OFF_SMALL + 667648);
    float* ssbuf     = (float*)(ws + OFF_SMALL + 671744);
    int*   flag      = (int*)(ws + OFF_SMALL + 675840);
    u16*  WprojT     = (u16*)(ws + OFF_SMALL + 679936);   // 131072 bytes

    // dtype probe first
    probe_k<<<1, 64, 0, stream>>>(x, flag);

    // prep (dtype-adaptive, transposed weights)
    wcat_k<<<256, 256, 0, stream>>>(Wqkv, Wres, Wproj, WcatT, WprojT, flag);
    biasprep_k<<<5, 256, 0, stream>>>(bqkv, bres, bproj, bias_cat, bias_proj, flag);
    wf_k<<<256, 256, 0, stream>>>(Wm1, Wm2, WfT, flag);
    bf_k<<<1, 256, 0, stream>>>(bm1, Wm2, bm2, bfv, flag);

    // qkv + res fused GEMM straight from x: (BN,256) @ (256,1024)
    gemm_qkv_k<<<1281, 256, 0, stream>>>(x, WcatT, bias_cat, qkvres, flag);

    // window attention: one block per (window, batch), all heads
    attn_k<TOPW><<<dim3(NTOP, B_), 256, 0, stream>>>(qkvres, top_idx, xw, 0);
    attn_k<DOWNW><<<dim3(NDOWN, B_), 256, 0, stream>>>(qkvres, down_idx, xw, NTOP * TOPW);

    // scatter-average back to points -> xf = qkvres cols 0..255 (q is dead)
    gather_k<<<(BN_ + 3) / 4, 256, 0, stream>>>(xw, rev, cnt_inv, qkvres, K, flag);

    // out = xf @ Wproj + bproj + res   (xf ldA=1024, res = qkvres cols 768..1023)
    gemm_k<true, false><<<1281, 256, 0, stream>>>(
        qkvres, 1024, WprojT, bias_proj, qkvres + 768, 1024, (void*)outb, 256, BN_);

    // res2 = out @ (Wm1@Wm2) + (bm1@Wm2+bm2)   (f32, overwrites dead qkvres front)
    gemm_k<false, true><<<1281, 256, 0, stream>>>(
        outb, 256, WfT, bfv, nullptr, 0, (void*)res2, 256, BN_);

    // batchnorm stats + finalize
    (void)hipMemsetAsync(stats, 0, 512 * sizeof(float), stream);
    stats_k<<<STATS_BLOCKS, 256, 0, stream>>>(res2, stats);
    bnfin_k<<<1, 256, 0, stream>>>(stats, gamma, beta, ssbuf, flag);

    // fused transpose + BN + residual add -> y (B, 256, N), dtype per flag
    final_k<<<dim3(641, 4, 2), 256, 0, stream>>>(outb, res2, ssbuf, d_out, flag);
}

// Round 14
// 781.208 us; speedup vs baseline: 1.2569x; 1.0952x over previous
//
#include <hip/hip_runtime.h>
#include <stdint.h>

typedef unsigned short u16;
typedef __bf16 bf16x8 __attribute__((ext_vector_type(8)));
typedef float f32x4 __attribute__((ext_vector_type(4)));

#define B_    2
#define C_    256
#define N_    40962
#define BN_   (B_ * N_)          // 81924
#define H_    8
#define HD_   32
#define NTOP  2562
#define TOPW  16
#define NDOWN 2562
#define DOWNW 19
#define M_    (NTOP*TOPW + NDOWN*DOWNW)   // 89670
#define SCALE_ 0.17677669529663687f       // 32^-0.5
#define BN_EPS 1e-5f

// ---------- bf16 helpers (raw u16 storage) ----------
__device__ __forceinline__ float b2f(u16 u) {
    union { uint32_t i; float f; } v; v.i = ((uint32_t)u) << 16; return v.f;
}
__device__ __forceinline__ u16 f2b(float f) {
    union { float f; uint32_t i; } v; v.f = f;
    uint32_t r = v.i + 0x7fffu + ((v.i >> 16) & 1u);   // RNE
    return (u16)(r >> 16);
}
// adaptive load: element i of a float tensor that is either f32 (isf32=1) or bf16
__device__ __forceinline__ float ld(const void* p, size_t i, int isf32) {
    return isf32 ? ((const float*)p)[i] : b2f(((const u16*)p)[i]);
}

// bijective XCD swizzle for grid=1281 (m204 formula; 1281 = 8*160 + 1)
__device__ __forceinline__ int xcd_swz_1281(int bx) {
    const int q = 160, r = 1;
    int xcd = bx & 7, o = bx >> 3;
    return (xcd < r ? xcd * (q + 1) : r * (q + 1) + (xcd - r) * q) + o;
}

// ---------- dtype probe: even u16 indices are garbage iff data is f32 ----------
__global__ void probe_k(const void* __restrict__ x, int* __restrict__ flag) {
    int lane = threadIdx.x;
    u16 v = ((const u16*)x)[2 * lane];
    int e = (v >> 7) & 0xff;
    bool ok = (e >= 118 && e <= 134);   // |val| in ~[2^-9, 2^8] -> plausible N(0,1) bf16
    unsigned long long m = __ballot(ok);
    if (lane == 0) *flag = (__popcll(m) < 32) ? 1 : 0;   // 1 = f32 inputs
}

// ---------- small prep kernels (dtype-adaptive) ----------
// Writes TRANSPOSED weights: WcatT[j][k] (1024x256), WprojT[j][k] (256x256)
__global__ void wcat_k(const void* __restrict__ Wqkv, const void* __restrict__ Wres,
                       const void* __restrict__ Wproj,
                       u16* __restrict__ WcatT, u16* __restrict__ WprojT,
                       const int* __restrict__ flag) {
    const int f = *flag;
    int k = blockIdx.x, t = threadIdx.x;
    for (int j = t; j < 768; j += 256) WcatT[(size_t)j * 256 + k] = f2b(ld(Wqkv, (size_t)k * 768 + j, f));
    WcatT[(size_t)(768 + t) * 256 + k] = f2b(ld(Wres, (size_t)k * 256 + t, f));
    WprojT[(size_t)t * 256 + k] = f2b(ld(Wproj, (size_t)k * 256 + t, f));
}

__global__ void biasprep_k(const void* bqkv, const void* bres, const void* bproj,
                           float* bias_cat, float* bias_proj, const int* __restrict__ flag) {
    const int f = *flag;
    int g = blockIdx.x * 256 + threadIdx.x;
    if (g < 768) bias_cat[g] = ld(bqkv, g, f);
    else if (g < 1024) bias_cat[g] = ld(bres, g - 768, f);
    else if (g < 1280) bias_proj[g - 1024] = ld(bproj, g - 1024, f);
}

// WfT[t][i] = (Wm1 @ Wm2)[i][t]   (transposed product), bf16 out
__global__ __launch_bounds__(256) void wf_k(const void* __restrict__ Wm1, const void* __restrict__ Wm2,
                                            u16* __restrict__ WfT, const int* __restrict__ flag) {
    const int f = *flag;
    __shared__ float row[512];
    int i = blockIdx.x, t = threadIdx.x;
    row[t] = ld(Wm1, (size_t)i * 512 + t, f);
    row[t + 256] = ld(Wm1, (size_t)i * 512 + 256 + t, f);
    __syncthreads();
    float acc = 0.f;
    for (int k = 0; k < 512; ++k) acc += row[k] * ld(Wm2, (size_t)k * 256 + t, f);
    WfT[(size_t)t * 256 + i] = f2b(acc);
}

// bf = bm1 @ Wm2 + bm2   (f32)
__global__ void bf_k(const void* bm1, const void* __restrict__ Wm2, const void* bm2,
                     float* bf, const int* __restrict__ flag) {
    const int f = *flag;
    int t = threadIdx.x;
    float acc = ld(bm2, t, f);
    for (int k = 0; k < 512; ++k) acc += ld(bm1, k, f) * ld(Wm2, (size_t)k * 256 + t, f);
    bf[t] = acc;
}

// ---------- QKV(+res) GEMM: A->LDS once, B register bursts, LDS-staged coalesced stores ----------
// Out(BN x 1024) = X^T(BN x 256) @ Wcat(256 x 1024) + bias_cat
__global__ __launch_bounds__(256) void gemm_qkv_k(
    const void* __restrict__ x, const u16* __restrict__ WcatT,
    const float* __restrict__ bias, u16* __restrict__ Out, const int* __restrict__ flag)
{
    const int isf32 = *flag;
    __shared__ __align__(16) u16 As[64][264];
    __shared__ __align__(16) u16 Ot[64][72];   // out-tile staging (row stride 144B, 16B-aligned)
    const int tid = threadIdx.x;
    const int bx = xcd_swz_1281(blockIdx.x);
    const int R0 = bx * 64;
    const int wave = tid >> 6, lane = tid & 63;
    const int quad = lane >> 4, mrow = lane & 15;
    const int srow = tid >> 2, schunk = (tid & 3) * 16;   // store-phase mapping

    // ---- stage A once into LDS ----
    const bool fastA = (R0 + 64 <= N_) || (R0 >= N_ && R0 + 64 <= BN_);
    if (fastA) {
        const int b = (R0 >= N_) ? 1 : 0;
        const int nn = R0 - b * N_;
        const int k = tid;
        if (isf32) {
            const float* xp = (const float*)x + (size_t)(b * 256 + k) * N_ + nn;
#pragma unroll
            for (int j = 0; j < 32; ++j) {
                float2 v = *reinterpret_cast<const float2*>(xp + 2 * j);
                As[2 * j][k] = f2b(v.x);
                As[2 * j + 1][k] = f2b(v.y);
            }
        } else {
            const u16* xp = (const u16*)x + (size_t)(b * 256 + k) * N_ + nn;
#pragma unroll
            for (int j = 0; j < 32; ++j) {
                uint32_t v = *reinterpret_cast<const uint32_t*>(xp + 2 * j);
                As[2 * j][k] = (u16)v;
                As[2 * j + 1][k] = (u16)(v >> 16);
            }
        }
    } else {
        const int n = tid & 63;
        const int kg = tid >> 6;
        const int g = R0 + n;
        const bool valid = (g < BN_);
        const int b = (g >= N_) ? 1 : 0;
        const int nn = g - b * N_;
#pragma unroll
        for (int j = 0; j < 8; ++j) {
            const int k0 = kg * 8 + j * 32;
            u16 tmp[8];
            if (valid) {
#pragma unroll
                for (int i = 0; i < 8; ++i) tmp[i] = f2b(ld(x, (size_t)(b * 256 + k0 + i) * N_ + nn, isf32));
            } else {
#pragma unroll
                for (int i = 0; i < 8; ++i) tmp[i] = 0;
            }
            *reinterpret_cast<uint4*>(&As[n][k0]) = *reinterpret_cast<const uint4*>(tmp);
        }
    }
    __syncthreads();   // As ready

    const bool rowOK = (R0 + 64 <= BN_);   // whole tile in range? (boundary block handles guards)

    for (int ct = 0; ct < 16; ++ct) {
        const int col = ct * 64 + wave * 16 + mrow;
        const u16* bp = WcatT + (size_t)col * 256 + quad * 8;
        // explicit burst: all 8 B fragments into named registers BEFORE compute
        uint4 breg[8];
#pragma unroll
        for (int kc = 0; kc < 8; ++kc) breg[kc] = *reinterpret_cast<const uint4*>(bp + kc * 32);
        f32x4 acc[4] = {f32x4{0,0,0,0}, f32x4{0,0,0,0}, f32x4{0,0,0,0}, f32x4{0,0,0,0}};
#pragma unroll
        for (int kc = 0; kc < 8; ++kc) {
            bf16x8 bfrag = *reinterpret_cast<const bf16x8*>(&breg[kc]);
#pragma unroll
            for (int t2 = 0; t2 < 4; ++t2) {
                bf16x8 afrag = *reinterpret_cast<const bf16x8*>(&As[t2 * 16 + mrow][kc * 32 + quad * 8]);
                acc[t2] = __builtin_amdgcn_mfma_f32_16x16x32_bf16(afrag, bfrag, acc[t2], 0, 0, 0);
            }
        }
        const float bcol = bias[col];
        __syncthreads();   // Ot free (previous tile's store-phase reads done)
#pragma unroll
        for (int t2 = 0; t2 < 4; ++t2) {
#pragma unroll
            for (int r = 0; r < 4; ++r) {
                Ot[t2 * 16 + quad * 4 + r][wave * 16 + mrow] = f2b(acc[t2][r] + bcol);
            }
        }
        __syncthreads();   // Ot ready
        // coalesced store: each thread writes 32B of one row (2x uint4)
        if (rowOK || (R0 + srow < BN_)) {
            const size_t ob = (size_t)(R0 + srow) * 1024 + ct * 64 + schunk;
            *reinterpret_cast<uint4*>(Out + ob)     = *reinterpret_cast<const uint4*>(&Ot[srow][schunk]);
            *reinterpret_cast<uint4*>(Out + ob + 8) = *reinterpret_cast<const uint4*>(&Ot[srow][schunk + 8]);
        }
    }
}

// ---------- generic MFMA GEMM: A->LDS once, B register bursts, f32 LDS-staged epilogue ----------
template<bool ADD_RES, bool OUT_F32>
__global__ __launch_bounds__(256) void gemm_k(
    const u16* __restrict__ A, int ldA, const u16* __restrict__ Bt,
    const float* __restrict__ bias,
    const u16* __restrict__ resp, int ldRes,
    void* __restrict__ Out, int ldOut, int Rtot)
{
    __shared__ __align__(16) u16 As[64][264];
    __shared__ __align__(16) float Otf[64][68];   // f32 out-tile staging (row stride 272B)
    const int tid = threadIdx.x;
    const int bx = xcd_swz_1281(blockIdx.x);
    const int R0 = bx * 64;
    const int wave = tid >> 6, lane = tid & 63;
    const int quad = lane >> 4, mrow = lane & 15;
    const int srow = tid >> 2, schunk = (tid & 3) * 16;   // store phase: 16 cols per thread

    // ---- stage A once: pure uint4 copies (A rows contiguous) ----
#pragma unroll
    for (int it = 0; it < 8; ++it) {
        int e = it * 256 + tid;
        int row = e >> 5, ks = (e & 31) * 8;
        uint4 v = make_uint4(0u, 0u, 0u, 0u);
        if (R0 + row < Rtot)
            v = *reinterpret_cast<const uint4*>(A + (size_t)(R0 + row) * ldA + ks);
        *reinterpret_cast<uint4*>(&As[row][ks]) = v;
    }
    __syncthreads();   // As ready

    const bool rowOK = (R0 + 64 <= Rtot);

    for (int ct = 0; ct < 4; ++ct) {
        const int col = ct * 64 + wave * 16 + mrow;
        const u16* bp = Bt + (size_t)col * 256 + quad * 8;
        uint4 breg[8];
#pragma unroll
        for (int kc = 0; kc < 8; ++kc) breg[kc] = *reinterpret_cast<const uint4*>(bp + kc * 32);
        f32x4 acc[4] = {f32x4{0,0,0,0}, f32x4{0,0,0,0}, f32x4{0,0,0,0}, f32x4{0,0,0,0}};
#pragma unroll
        for (int kc = 0; kc < 8; ++kc) {
            bf16x8 bfrag = *reinterpret_cast<const bf16x8*>(&breg[kc]);
#pragma unroll
            for (int t2 = 0; t2 < 4; ++t2) {
                bf16x8 afrag = *reinterpret_cast<const bf16x8*>(&As[t2 * 16 + mrow][kc * 32 + quad * 8]);
                acc[t2] = __builtin_amdgcn_mfma_f32_16x16x32_bf16(afrag, bfrag, acc[t2], 0, 0, 0);
            }
        }
        const float bcol = bias[col];
        __syncthreads();   // Otf free
#pragma unroll
        for (int t2 = 0; t2 < 4; ++t2) {
#pragma unroll
            for (int r = 0; r < 4; ++r) {
                Otf[t2 * 16 + quad * 4 + r][wave * 16 + mrow] = acc[t2][r] + bcol;
            }
        }
        __syncthreads();   // Otf ready
        if (rowOK || (R0 + srow < Rtot)) {
            const int row = R0 + srow;
            const int colbase = ct * 64 + schunk;
            float v[16];
#pragma unroll
            for (int j = 0; j < 16; ++j) v[j] = Otf[srow][schunk + j];
            if (ADD_RES) {
                uint4 rv0 = *reinterpret_cast<const uint4*>(resp + (size_t)row * ldRes + colbase);
                uint4 rv1 = *reinterpret_cast<const uint4*>(resp + (size_t)row * ldRes + colbase + 8);
                const u16* rp0 = (const u16*)&rv0;
                const u16* rp1 = (const u16*)&rv1;
#pragma unroll
                for (int j = 0; j < 8; ++j) { v[j] += b2f(rp0[j]); v[8 + j] += b2f(rp1[j]); }
            }
            if (OUT_F32) {
                float* op = (float*)Out + (size_t)row * ldOut + colbase;
#pragma unroll
                for (int q = 0; q < 4; ++q)
                    *reinterpret_cast<float4*>(op + q * 4) = make_float4(v[q*4], v[q*4+1], v[q*4+2], v[q*4+3]);
            } else {
                u16 ob[16];
#pragma unroll
                for (int j = 0; j < 16; ++j) ob[j] = f2b(v[j]);
                u16* op = (u16*)Out + (size_t)row * ldOut + colbase;
                *reinterpret_cast<uint4*>(op)     = *reinterpret_cast<const uint4*>(&ob[0]);
                *reinterpret_cast<uint4*>(op + 8) = *reinterpret_cast<const uint4*>(&ob[8]);
            }
        }
    }
}

// ---------- window attention (one block = one window x one batch, all 8 heads) ----------
template<int W>
__global__ __launch_bounds__(256) void attn_k(const u16* __restrict__ qkv, const int* __restrict__ widx,
                                              u16* __restrict__ xw, int mbase)
{
    const int w = blockIdx.x, b = blockIdx.y;
    const int tid = threadIdx.x;
    __shared__ int wi[W];
    __shared__ __align__(16) float Ks[W][H_][36];
    __shared__ __align__(16) float Vs[W][H_][36];
    if (tid < W) wi[tid] = widx[w * W + tid];
    __syncthreads();
    for (int e = tid; e < W * 32; e += 256) {
        int j = e >> 5, seg = e & 31;
        size_t base = ((size_t)(b * N_ + wi[j])) * 1024 + 256 + seg * 8;
        uint4 kv = *reinterpret_cast<const uint4*>(qkv + base);         // K
        uint4 vv = *reinterpret_cast<const uint4*>(qkv + base + 256);   // V
        int h = seg >> 2, c0 = (seg & 3) * 8;
        const u16* kp = (const u16*)&kv; const u16* vp = (const u16*)&vv;
#pragma unroll
        for (int t = 0; t < 8; ++t) {
            Ks[j][h][c0 + t] = b2f(kp[t]);
            Vs[j][h][c0 + t] = b2f(vp[t]);
        }
    }
    __syncthreads();

    if (tid < W * H_) {
        const int j = tid >> 3, h = tid & 7;
        float qr[32];
        {
            size_t qb = ((size_t)(b * N_ + wi[j])) * 1024 + h * 32;
#pragma unroll
            for (int s4 = 0; s4 < 4; ++s4) {
                uint4 qv = *reinterpret_cast<const uint4*>(qkv + qb + s4 * 8);
                const u16* qp = (const u16*)&qv;
#pragma unroll
                for (int t = 0; t < 8; ++t) qr[s4 * 8 + t] = b2f(qp[t]) * SCALE_;
            }
        }
        float p[W];
        float mx = -1e30f;
#pragma unroll
        for (int jj = 0; jj < W; ++jj) {
            const float* kr = &Ks[jj][h][0];
            float s = 0.f;
#pragma unroll
            for (int c = 0; c < 32; ++c) s += qr[c] * kr[c];
            p[jj] = s;
            mx = fmaxf(mx, s);
        }
        float sum = 0.f;
#pragma unroll
        for (int jj = 0; jj < W; ++jj) { p[jj] = __expf(p[jj] - mx); sum += p[jj]; }
        const float inv = 1.0f / sum;
        float o[32];
#pragma unroll
        for (int c = 0; c < 32; ++c) o[c] = 0.f;
#pragma unroll
        for (int jj = 0; jj < W; ++jj) {
            const float pj = p[jj];
            const float* vr = &Vs[jj][h][0];
#pragma unroll
            for (int c = 0; c < 32; ++c) o[c] += pj * vr[c];
        }
        const int m = mbase + w * W + j;
        size_t off = ((size_t)b * (M_ + 1) + m) * 256 + h * 32;
#pragma unroll
        for (int s4 = 0; s4 < 4; ++s4) {
            uint32_t w0 = (uint32_t)f2b(o[s4 * 8 + 0] * inv) | ((uint32_t)f2b(o[s4 * 8 + 1] * inv) << 16);
            uint32_t w1 = (uint32_t)f2b(o[s4 * 8 + 2] * inv) | ((uint32_t)f2b(o[s4 * 8 + 3] * inv) << 16);
            uint32_t w2 = (uint32_t)f2b(o[s4 * 8 + 4] * inv) | ((uint32_t)f2b(o[s4 * 8 + 5] * inv) << 16);
            uint32_t w3 = (uint32_t)f2b(o[s4 * 8 + 6] * inv) | ((uint32_t)f2b(o[s4 * 8 + 7] * inv) << 16);
            *reinterpret_cast<uint4*>(xw + off + s4 * 8) = make_uint4(w0, w1, w2, w3);
        }
    }
}

// ---------- gather + average -> xf written into qkvres cols 0..255 (ld 1024) ----------
__global__ __launch_bounds__(256) void gather_k(const u16* __restrict__ xw, const int* __restrict__ rev,
                                                const void* __restrict__ cnt_inv, u16* __restrict__ xfp,
                                                int K, const int* __restrict__ flag)
{
    const int f = *flag;
    int gid = blockIdx.x * 4 + (threadIdx.x >> 6);
    if (gid >= BN_) return;
    int b = (gid >= N_) ? 1 : 0;
    int n = gid - b * N_;
    int c4 = (threadIdx.x & 63) * 4;
    float a0 = 0, a1 = 0, a2 = 0, a3 = 0;
    const int* rp = rev + (size_t)n * K;
    for (int k = 0; k < K; ++k) {
        int idx = rp[k];
        if (idx < M_) {
            ushort4 v = *reinterpret_cast<const ushort4*>(xw + ((size_t)b * (M_ + 1) + idx) * 256 + c4);
            a0 += b2f(v.x); a1 += b2f(v.y); a2 += b2f(v.z); a3 += b2f(v.w);
        }
    }
    float ci = ld(cnt_inv, n, f);
    ushort4 o;
    o.x = f2b(a0 * ci); o.y = f2b(a1 * ci); o.z = f2b(a2 * ci); o.w = f2b(a3 * ci);
    *reinterpret_cast<ushort4*>(xfp + (size_t)gid * 1024 + c4) = o;
}

// ---------- BN stats over res2 (BN_ x 256 f32): per-column sum & sumsq ----------
#define STATS_BLOCKS 512
__global__ __launch_bounds__(256) void stats_k(const float* __restrict__ res2, float* __restrict__ sums) {
    const int tid = threadIdx.x;
    const int c4 = (tid & 63) * 4;    // column group
    const int rsub = tid >> 6;        // 0..3 (which row of the 4-row slab)
    float s[4] = {0.f, 0.f, 0.f, 0.f};
    float q[4] = {0.f, 0.f, 0.f, 0.f};
    for (int r = blockIdx.x * 4 + rsub; r < BN_; r += STATS_BLOCKS * 4) {
        float4 v = *reinterpret_cast<const float4*>(res2 + (size_t)r * 256 + c4);
        s[0] += v.x; q[0] += v.x * v.x;
        s[1] += v.y; q[1] += v.y * v.y;
        s[2] += v.z; q[2] += v.z * v.z;
        s[3] += v.w; q[3] += v.w * v.w;
    }
    __shared__ float rs[256][4];
    __shared__ float rq[256][4];
#pragma unroll
    for (int j = 0; j < 4; ++j) { rs[tid][j] = s[j]; rq[tid][j] = q[j]; }
    __syncthreads();
    if (tid < 64) {
#pragma unroll
        for (int j = 0; j < 4; ++j) {
            float a = rs[tid][j] + rs[tid + 64][j] + rs[tid + 128][j] + rs[tid + 192][j];
            float b = rq[tid][j] + rq[tid + 64][j] + rq[tid + 128][j] + rq[tid + 192][j];
            atomicAdd(&sums[c4 + j], a);
            atomicAdd(&sums[256 + c4 + j], b);
        }
    }
}

__global__ void bnfin_k(const float* sums, const void* gamma, const void* beta, float* ss,
                        const int* __restrict__ flag) {
    const int f = *flag;
    int c = threadIdx.x;
    float mean = sums[c] * (1.0f / BN_);
    float var = sums[256 + c] * (1.0f / BN_) - mean * mean;
    float inv = rsqrtf(fmaxf(var, 0.f) + BN_EPS);
    float sc = ld(gamma, c, f) * inv;
    ss[c] = sc;
    ss[256 + c] = ld(beta, c, f) - mean * sc;
}

// ---------- final: y[b,oc,n] = out[b,n,oc] + res2[b,n,oc]*scale[oc] + shift[oc] ----------
__global__ __launch_bounds__(256) void final_k(const u16* __restrict__ outb, const float* __restrict__ res2,
                                               const float* __restrict__ ss, void* __restrict__ y,
                                               const int* __restrict__ flag)
{
    const int isf32 = *flag;
    __shared__ __align__(16) float tile[64][65];
    const int n0 = blockIdx.x * 64, o0 = blockIdx.y * 64, b = blockIdx.z;
    const int tid = threadIdx.x;
    {
        const int ln = tid >> 2, os = (tid & 3) * 16;
        int n = n0 + ln;
        if (n < N_) {
            size_t base = ((size_t)(b * N_ + n)) * 256 + o0 + os;
            uint4 ov0 = *reinterpret_cast<const uint4*>(outb + base);
            uint4 ov1 = *reinterpret_cast<const uint4*>(outb + base + 8);
            const u16* op = (const u16*)&ov0;
            const u16* op1 = (const u16*)&ov1;
            float4 rv[4];
#pragma unroll
            for (int q = 0; q < 4; ++q) rv[q] = *reinterpret_cast<const float4*>(res2 + base + q * 4);
            const float* rp = (const float*)&rv[0];
#pragma unroll
            for (int j = 0; j < 16; ++j) {
                int oc = o0 + os + j;
                float ob = (j < 8) ? b2f(op[j]) : b2f(op1[j - 8]);
                tile[ln][os + j] = ob + rp[j] * ss[oc] + ss[256 + oc];
            }
        }
    }
    __syncthreads();
    {
        const int wave = tid >> 6, lane = tid & 63;
        int n = n0 + lane;
        if (n < N_) {
            if (isf32) {
                float* yp = (float*)y;
#pragma unroll
                for (int r0 = 0; r0 < 64; r0 += 4) {
                    int r = r0 + wave;
                    int oc = o0 + r;
                    yp[((size_t)(b * 256 + oc)) * N_ + n] = tile[lane][r];
                }
            } else {
                u16* yp = (u16*)y;
#pragma unroll
                for (int r0 = 0; r0 < 64; r0 += 4) {
                    int r = r0 + wave;
                    int oc = o0 + r;
                    yp[((size_t)(b * 256 + oc)) * N_ + n] = f2b(tile[lane][r]);
                }
            }
        }
    }
}

// ---------- workspace layout (bytes) ----------
static const size_t OFF_QKV   = 0;
static const size_t OFF_XW    = 167780352;
static const size_t OFF_SMALL = 259603456;

extern "C" void kernel_launch(void* const* d_in, const int* in_sizes, int n_in,
                              void* d_out, int out_size, void* d_ws, size_t ws_size,
                              hipStream_t stream) {
    const void* x     = d_in[0];
    const void* Wqkv  = d_in[1];
    const void* bqkv  = d_in[2];
    const void* Wproj = d_in[3];
    const void* bproj = d_in[4];
    const void* Wres  = d_in[5];
    const void* bres  = d_in[6];
    const void* Wm1   = d_in[7];
    const void* bm1   = d_in[8];
    const void* Wm2   = d_in[9];
    const void* bm2   = d_in[10];
    const void* gamma = d_in[11];
    const void* beta  = d_in[12];
    const void* cnt_inv = d_in[13];
    const int* top_idx = (const int*)d_in[14];
    const int* down_idx = (const int*)d_in[15];
    const int* rev   = (const int*)d_in[16];
    const int K = in_sizes[16] / N_;

    char* ws = (char*)d_ws;
    u16*  qkvres  = (u16*)(ws + OFF_QKV);
    float* res2   = (float*)(ws + OFF_QKV);
    u16*  xw      = (u16*)(ws + OFF_XW);
    u16*  outb    = (u16*)(ws + OFF_XW);
    u16*  WcatT   = (u16*)(ws + OFF_SMALL);
    u16*  WfT     = (u16*)(ws + OFF_SMALL + 524288);
    float* bias_cat  = (float*)(ws + OFF_SMALL + 655360);
    float* bias_proj = (float*)(ws + OFF_SMALL + 659456);
    float* bfv       = (float*)(ws + OFF_SMALL + 663552);
    float* stats     = (float*)(ws + OFF_SMALL + 667648);
    float* ssbuf     = (float*)(ws + OFF_SMALL + 671744);
    int*   flag      = (int*)(ws + OFF_SMALL + 675840);
    u16*  WprojT     = (u16*)(ws + OFF_SMALL + 679936);   // 131072 bytes

    // dtype probe first
    probe_k<<<1, 64, 0, stream>>>(x, flag);

    // prep (dtype-adaptive, transposed weights)
    wcat_k<<<256, 256, 0, stream>>>(Wqkv, Wres, Wproj, WcatT, WprojT, flag);
    biasprep_k<<<5, 256, 0, stream>>>(bqkv, bres, bproj, bias_cat, bias_proj, flag);
    wf_k<<<256, 256, 0, stream>>>(Wm1, Wm2, WfT, flag);
    bf_k<<<1, 256, 0, stream>>>(bm1, Wm2, bm2, bfv, flag);

    // qkv + res fused GEMM straight from x: (BN,256) @ (256,1024)
    gemm_qkv_k<<<1281, 256, 0, stream>>>(x, WcatT, bias_cat, qkvres, flag);

    // window attention: one block per (window, batch), all heads
    attn_k<TOPW><<<dim3(NTOP, H_ == 8 ? B_ : B_), 256, 0, stream>>>(qkvres, top_idx, xw, 0);
    attn_k<DOWNW><<<dim3(NDOWN, B_), 256, 0, stream>>>(qkvres, down_idx, xw, NTOP * TOPW);

    // scatter-average back to points -> xf = qkvres cols 0..255 (q is dead)
    gather_k<<<(BN_ + 3) / 4, 256, 0, stream>>>(xw, rev, cnt_inv, qkvres, K, flag);

    // out = xf @ Wproj + bproj + res   (xf ldA=1024, res = qkvres cols 768..1023)
    gemm_k<true, false><<<1281, 256, 0, stream>>>(
        qkvres, 1024, WprojT, bias_proj, qkvres + 768, 1024, (void*)outb, 256, BN_);

    // res2 = out @ (Wm1@Wm2) + (bm1@Wm2+bm2)   (f32, overwrites dead qkvres front)
    gemm_k<false, true><<<1281, 256, 0, stream>>>(
        outb, 256, WfT, bfv, nullptr, 0, (void*)res2, 256, BN_);

    // batchnorm stats + finalize
    (void)hipMemsetAsync(stats, 0, 512 * sizeof(float), stream);
    stats_k<<<STATS_BLOCKS, 256, 0, stream>>>(res2, stats);
    bnfin_k<<<1, 256, 0, stream>>>(stats, gamma, beta, ssbuf, flag);

    // fused transpose + BN + residual add -> y (B, 256, N), dtype per flag
    final_k<<<dim3(641, 4, 2), 256, 0, stream>>>(outb, res2, ssbuf, d_out, flag);
}